// Round 6
// baseline (514.249 us; speedup 1.0000x reference)
//
#include <hip/hip_runtime.h>

#define NTHREADS 256

// problem constants
constexpr int R1c  = 2048;
constexpr int R2c  = 2624;
constexpr float EPSc = 1e-5f;

// ws float offsets (stats)
constexpr int SLOTS1  = 0;
constexpr int SLOTS1Q = 4096;
constexpr int SLOTS2  = 8192;
constexpr int SLOTS2Q = 12288;
constexpr int SLOTS3  = 16384;
constexpr int SLOTS3Q = 18432;
constexpr int FIN1    = 20480;
constexpr int FIN2    = 20608;
constexpr int FIN3    = 20736;
constexpr int STATS_ZERO_FLOATS = 20480;

// ws byte offsets
constexpr size_t ZB_OFF = 131072;                    // z bf16 [8192 patch][4096]
constexpr size_t OB_OFF = ZB_OFF + 8192ull*4096*2;   // o bf16 [8192 patch][2048]

// ---- bf16 helpers -------------------------------------------------------
__device__ __forceinline__ ushort f_to_bf16(float f) {
    union { float f; unsigned int i; } v; v.f = f;
    unsigned int r = (v.i + 0x7fffu + ((v.i >> 16) & 1u)) >> 16;
    return (ushort)r;
}
__device__ __forceinline__ float bf16_to_f(ushort u) {
    union { unsigned int i; float f; } v; v.i = ((unsigned int)u) << 16; return v.f;
}
__device__ __forceinline__ float bf16lo_to_f(unsigned int u) {
    union { unsigned int i; float f; } v; v.i = u << 16; return v.f;
}
__device__ __forceinline__ float bf16hi_to_f(unsigned int u) {
    union { unsigned int i; float f; } v; v.i = u & 0xffff0000u; return v.f;
}
__device__ __forceinline__ unsigned int pack_bf16(float lo, float hi) {
    return (unsigned int)f_to_bf16(lo) | ((unsigned int)f_to_bf16(hi) << 16);
}

typedef short bf16x8 __attribute__((ext_vector_type(8)));
typedef float f32x4  __attribute__((ext_vector_type(4)));
union U8 { bf16x8 v; uint2 d2[2]; unsigned int d1[4]; };

__device__ __forceinline__ f32x4 mfma16(bf16x8 a, bf16x8 b, f32x4 c) {
    return __builtin_amdgcn_mfma_f32_16x16x32_bf16(a, b, c, 0, 0, 0);
}
// 8B-aligned LDS frag load (two ds_read_b64)
__device__ __forceinline__ bf16x8 ldsf8(const ushort* p) {
    U8 r; r.d2[0] = *(const uint2*)p; r.d2[1] = *(const uint2*)(p + 4); return r.v;
}
// 4B-aligned LDS frag load (four ds_read_b32)
__device__ __forceinline__ bf16x8 ldsf4(const ushort* p) {
    U8 r;
    r.d1[0] = *(const unsigned int*)p;
    r.d1[1] = *(const unsigned int*)(p + 2);
    r.d1[2] = *(const unsigned int*)(p + 4);
    r.d1[3] = *(const unsigned int*)(p + 6);
    return r.v;
}

// block id decode: wgid = group + j*256 so the 8 siblings (same group=(bi,f))
// share an XCD under round-robin dispatch.
__device__ __forceinline__ void decode_blk(int wg, int& bi, int& f, int& gq, int& orig) {
    int group = wg & 255, j = wg >> 8;
    orig = group * 8 + j;
    bi = group >> 5; f = group & 31; gq = j;
}

// ---------------------------------------------------------------------------
// K1: stats1. 4 patches/block, wave-per-patch MFMA (M=64,N=112,K=32).
__global__ __launch_bounds__(NTHREADS)
void k1_mf(const float* __restrict__ x, const float* __restrict__ s,
           float* __restrict__ ws) {
    __shared__ char smem[51296];
    ushort* frA = (ushort*)smem;             // [4][64 rows][36], stride 2308
    ushort* frB = (ushort*)(smem + 18464);   // [4][112 rows][36], stride 4040
    float*  st1 = (float*)(smem + 50784);    // [128]

    const int t = threadIdx.x;
    int bi, f, gq, orig; decode_blk(blockIdx.x, bi, f, gq, orig);
    const int slot = orig & 63;
    const int goff = f * 32 + gq * 4;

    if (t < 128) st1[t] = 0.f;
    // zero pad rows (px 100..111) of frB
    for (int i = t; i < 864; i += NTHREADS) {
        int p = i / 216, r = i - p * 216;
        ((unsigned int*)(frB + p * 4040 + 3600))[r] = 0u;
    }
    // stage w1 (param p = ch*32+c; 4 consecutive floats = 4 patches)
    {
        const float* sp = s + (size_t)bi * 4672 * 1024 + goff;
        int pp = t >> 2, q = t & 3;
        #pragma unroll 4
        for (int it = 0; it < 32; ++it) {
            float v = sp[(size_t)(pp * 32 + it) * 1024 + q];
            frA[q * 2308 + pp * 36 + it] = f_to_bf16(v);
        }
    }
    // stage x (34-wide rows with reflect halo; cols split across 4 patches)
    {
        const float* xb = x + (size_t)bi * 32 * 65536;
        for (int i = t; i < 10880; i += NTHREADS) {
            int c = i / 340, rem = i - c * 340;
            int r = rem / 34, jj = rem - r * 34;
            int row = f * 8 - 1 + r; row = row < 0 ? -row : (row > 255 ? 510 - row : row);
            int col = gq * 32 - 1 + jj; col = col < 0 ? -col : (col > 255 ? 510 - col : col);
            ushort v = f_to_bf16(xb[(size_t)c * 65536 + row * 256 + col]);
            int pEnd = jj >> 3; if (pEnd > 3) pEnd = 3;
            int pBeg = (jj >= 10) ? ((jj - 2) >> 3) : 0;
            for (int p = pBeg; p <= pEnd; ++p) {
                int pc = jj - p * 8;
                if (pc < 10) frB[p * 4040 + (r * 10 + pc) * 36 + c] = v;
            }
        }
    }
    __syncthreads();

    const int w = t >> 6, l = t & 63, l15 = l & 15, grp = l >> 4;
    bf16x8 bfr[7];
    {
        const ushort* bb = frB + w * 4040 + grp * 8;
        #pragma unroll
        for (int n = 0; n < 7; n++) bfr[n] = ldsf8(bb + (n * 16 + l15) * 36);
    }
    float s4[16], q4[16];
    #pragma unroll
    for (int i = 0; i < 16; i++) { s4[i] = 0.f; q4[i] = 0.f; }
    const ushort* ab = frA + w * 2308 + grp * 8;
    #pragma unroll
    for (int m = 0; m < 4; m++) {
        bf16x8 a = ldsf8(ab + (m * 16 + l15) * 36);
        #pragma unroll
        for (int n = 0; n < 7; n++) {
            f32x4 z = {0.f, 0.f, 0.f, 0.f};
            f32x4 c = mfma16(a, bfr[n], z);
            #pragma unroll
            for (int r = 0; r < 4; r++) { float v = c[r]; s4[m*4+r] += v; q4[m*4+r] += v * v; }
        }
    }
    #pragma unroll
    for (int i = 0; i < 16; i++) {
        float sm = s4[i], qq = q4[i];
        #pragma unroll
        for (int msk = 1; msk <= 8; msk <<= 1) { sm += __shfl_xor(sm, msk); qq += __shfl_xor(qq, msk); }
        if (l15 == 0) {
            int ch = (i >> 2) * 16 + grp * 4 + (i & 3);
            atomicAdd(&st1[ch], sm);
            atomicAdd(&st1[64 + ch], qq);
        }
    }
    __syncthreads();
    if (t < 64) {
        atomicAdd(&ws[SLOTS1  + t * 64 + slot], st1[t]);
        atomicAdd(&ws[SLOTS1Q + t * 64 + slot], st1[64 + t]);
    }
}

// ---------------------------------------------------------------------------
// K2: recompute stage-1 (MFMA), BN1+relu6 -> per-m 16-ch y slice in LDS,
//     depthwise 3x3, stats2, store z bf16.
__global__ __launch_bounds__(NTHREADS)
void k2_mf(const float* __restrict__ x, const float* __restrict__ s,
           ushort* __restrict__ zbuf, float* __restrict__ ws) {
    __shared__ char smem[65216];
    ushort* frA = (ushort*)smem;             // [4][64][36], stride 2308
    ushort* frB = (ushort*)(smem + 18464);   // [4][100 rows][36], stride 3604 (+overread into slc)
    ushort* slc = (ushort*)(smem + 47296);   // [4][16 ch][100]
    ushort* w2s = (ushort*)(smem + 60096);   // [4][576]
    float*  fst = (float*)(smem + 64704);    // [128]: fin1 early, stats2 late

    const int t = threadIdx.x;
    int bi, f, gq, orig; decode_blk(blockIdx.x, bi, f, gq, orig);
    const int slot = orig & 63;
    const int goff = f * 32 + gq * 4;
    const int Pb = bi * 1024 + f * 32 + gq * 4;

    if (t < 128) fst[t] = ws[FIN1 + t];
    const float* sp = s + (size_t)bi * 4672 * 1024 + goff;
    {
        int pp = t >> 2, q = t & 3;
        #pragma unroll 4
        for (int it = 0; it < 32; ++it) {
            float v = sp[(size_t)(pp * 32 + it) * 1024 + q];
            frA[q * 2308 + pp * 36 + it] = f_to_bf16(v);
        }
        #pragma unroll
        for (int it = 0; it < 9; ++it) {
            int i = pp + 64 * it;
            w2s[q * 576 + i] = f_to_bf16(sp[(size_t)(R1c + i) * 1024 + q]);
        }
    }
    {
        const float* xb = x + (size_t)bi * 32 * 65536;
        for (int i = t; i < 10880; i += NTHREADS) {
            int c = i / 340, rem = i - c * 340;
            int r = rem / 34, jj = rem - r * 34;
            int row = f * 8 - 1 + r; row = row < 0 ? -row : (row > 255 ? 510 - row : row);
            int col = gq * 32 - 1 + jj; col = col < 0 ? -col : (col > 255 ? 510 - col : col);
            ushort v = f_to_bf16(xb[(size_t)c * 65536 + row * 256 + col]);
            int pEnd = jj >> 3; if (pEnd > 3) pEnd = 3;
            int pBeg = (jj >= 10) ? ((jj - 2) >> 3) : 0;
            for (int p = pBeg; p <= pEnd; ++p) {
                int pc = jj - p * 8;
                if (pc < 10) frB[p * 3604 + (r * 10 + pc) * 36 + c] = v;
            }
        }
    }
    __syncthreads();

    const int w = t >> 6, l = t & 63, l15 = l & 15, grp = l >> 4;
    const int ch_l = l >> 2, quad = l & 3, p0 = quad * 2;
    bf16x8 bfr[7];
    {
        const ushort* bb = frB + w * 3604 + grp * 8;
        #pragma unroll
        for (int n = 0; n < 7; n++) bfr[n] = ldsf8(bb + (n * 16 + l15) * 36); // n=6 overreads garbage rows (discarded)
    }
    const ushort* ab = frA + w * 2308 + grp * 8;
    ushort* slw = slc + w * 1600;
    float zsum[4], zsq[4];

    #pragma unroll
    for (int m = 0; m < 4; m++) {
        bf16x8 a = ldsf8(ab + (m * 16 + l15) * 36);
        f32x4 acc[7];
        #pragma unroll
        for (int n = 0; n < 7; n++) {
            f32x4 z = {0.f, 0.f, 0.f, 0.f};
            acc[n] = mfma16(a, bfr[n], z);
        }
        // BN1 + relu6 -> y slice (16 ch of this m)
        #pragma unroll
        for (int n = 0; n < 7; n++) {
            int px = n * 16 + l15;
            if (px < 100) {
                #pragma unroll
                for (int r = 0; r < 4; r++) {
                    int ch = m * 16 + grp * 4 + r;
                    float v = fminf(fmaxf(acc[n][r] * fst[ch] + fst[64 + ch], 0.f), 6.f);
                    slw[(grp * 4 + r) * 100 + px] = f_to_bf16(v);
                }
            }
        }
        // depthwise 3x3 (lane = ch_l, quad rows); in-wave LDS ordering is program order
        float yv[4][10];
        #pragma unroll
        for (int rr = 0; rr < 4; rr++)
            #pragma unroll
            for (int cc = 0; cc < 10; cc++)
                yv[rr][cc] = bf16_to_f(slw[ch_l * 100 + (p0 + rr) * 10 + cc]);
        float wt[9];
        #pragma unroll
        for (int k = 0; k < 9; k++)
            wt[k] = bf16_to_f(w2s[w * 576 + (m * 16 + ch_l) * 9 + k]);
        float za[2][8];
        #pragma unroll
        for (int rr = 0; rr < 2; rr++)
            #pragma unroll
            for (int qq = 0; qq < 8; qq++) za[rr][qq] = 0.f;
        #pragma unroll
        for (int u = 0; u < 3; u++)
            #pragma unroll
            for (int v = 0; v < 3; v++) {
                float wv = wt[u * 3 + v];
                #pragma unroll
                for (int rr = 0; rr < 2; rr++)
                    #pragma unroll
                    for (int qq = 0; qq < 8; qq++)
                        za[rr][qq] += wv * yv[rr + u][qq + v];
            }
        float zs = 0.f, zq = 0.f;
        #pragma unroll
        for (int rr = 0; rr < 2; rr++)
            #pragma unroll
            for (int qq = 0; qq < 8; qq++) { float v = za[rr][qq]; zs += v; zq += v * v; }
        zsum[m] = zs; zsq[m] = zq;
        // store z bf16
        ushort* zp = zbuf + (size_t)(Pb + w) * 4096 + (m * 16 + ch_l) * 64 + p0 * 8;
        uint4 pk0, pk1;
        pk0.x = pack_bf16(za[0][0], za[0][1]); pk0.y = pack_bf16(za[0][2], za[0][3]);
        pk0.z = pack_bf16(za[0][4], za[0][5]); pk0.w = pack_bf16(za[0][6], za[0][7]);
        pk1.x = pack_bf16(za[1][0], za[1][1]); pk1.y = pack_bf16(za[1][2], za[1][3]);
        pk1.z = pack_bf16(za[1][4], za[1][5]); pk1.w = pack_bf16(za[1][6], za[1][7]);
        *(uint4*)zp = pk0;
        *(uint4*)(zp + 8) = pk1;
    }
    // stats2: quad-reduce, LDS-accumulate (fst reused), then one push per ch
    __syncthreads();
    if (t < 128) fst[t] = 0.f;
    __syncthreads();
    #pragma unroll
    for (int m = 0; m < 4; m++) {
        float zs = zsum[m], zq = zsq[m];
        zs += __shfl_xor(zs, 1); zs += __shfl_xor(zs, 2);
        zq += __shfl_xor(zq, 1); zq += __shfl_xor(zq, 2);
        if (quad == 0) {
            atomicAdd(&fst[m * 16 + ch_l], zs);
            atomicAdd(&fst[64 + m * 16 + ch_l], zq);
        }
    }
    __syncthreads();
    if (t < 64) {
        atomicAdd(&ws[SLOTS2  + t * 64 + slot], fst[t]);
        atomicAdd(&ws[SLOTS2Q + t * 64 + slot], fst[64 + t]);
    }
}

// ---------------------------------------------------------------------------
// K3: z bf16 -> BN2+relu6 -> MFMA stage-3 (M=32,N=64,K=64), stats3, o bf16.
__global__ __launch_bounds__(NTHREADS)
void k3_mf(const ushort* __restrict__ zbuf, const float* __restrict__ s,
           ushort* __restrict__ obuf, float* __restrict__ ws) {
    __shared__ char smem[57472];
    ushort* frA = (ushort*)smem;             // w3 [4][32 rows][72], stride 2308
    ushort* zB  = (ushort*)(smem + 18464);   // z  [4][64 px rows][74], stride 4744; o_lds overlays
    float*  fin2 = (float*)(smem + 56416);   // [128]
    float*  st3  = (float*)(smem + 56928);   // [64]

    const int t = threadIdx.x;
    int bi, f, gq, orig; decode_blk(blockIdx.x, bi, f, gq, orig);
    const int slot = orig & 63;
    const int goff = f * 32 + gq * 4;
    const int Pb = bi * 1024 + f * 32 + gq * 4;

    if (t < 128) fin2[t] = ws[FIN2 + t];
    if (t < 64) st3[t] = 0.f;
    // stage w3 (param = R2c + oc*64 + ch)
    {
        const float* sp = s + (size_t)bi * 4672 * 1024 + goff;
        int pp = t >> 2, q = t & 3;
        #pragma unroll 4
        for (int it = 0; it < 32; ++it) {
            int i = pp + 64 * it;
            int oc = i & 31, chh = i >> 5;
            float v = sp[(size_t)(R2c + oc * 64 + chh) * 1024 + q];
            frA[q * 2308 + oc * 72 + chh] = f_to_bf16(v);
        }
    }
    __syncthreads();   // fin2 ready
    // stage z: BN2+relu6, transpose [ch][px] -> [px][ch^swz]
    for (int ii = t; ii < 2048; ii += NTHREADS) {
        int pp = ii >> 9, idx = ii & 511;
        int ch = idx >> 3, px0 = (idx & 7) * 8;
        uint4 v = ((const uint4*)(zbuf + (size_t)(Pb + pp) * 4096))[idx];
        float a2 = fin2[ch], b2 = fin2[64 + ch];
        ushort* zp = zB + pp * 4744;
        unsigned int uu[4] = {v.x, v.y, v.z, v.w};
        #pragma unroll
        for (int k = 0; k < 4; k++) {
            float lo = fminf(fmaxf(bf16lo_to_f(uu[k]) * a2 + b2, 0.f), 6.f);
            float hi = fminf(fmaxf(bf16hi_to_f(uu[k]) * a2 + b2, 0.f), 6.f);
            int pxa = px0 + 2 * k, pxb = pxa + 1;
            zp[pxa * 74 + (ch ^ ((pxa & 7) << 3))] = f_to_bf16(lo);
            zp[pxb * 74 + (ch ^ ((pxb & 7) << 3))] = f_to_bf16(hi);
        }
    }
    __syncthreads();

    const int w = t >> 6, l = t & 63, l15 = l & 15, grp = l >> 4;
    bf16x8 afr[2][2], bfr[2][4];
    {
        const ushort* ab = frA + w * 2308;
        #pragma unroll
        for (int m = 0; m < 2; m++)
            #pragma unroll
            for (int ks = 0; ks < 2; ks++)
                afr[m][ks] = ldsf8(ab + (m * 16 + l15) * 72 + ks * 32 + grp * 8);
        const ushort* zb = zB + w * 4744;
        int sw = (l & 7) << 3;
        #pragma unroll
        for (int ks = 0; ks < 2; ks++)
            #pragma unroll
            for (int n = 0; n < 4; n++)
                bfr[ks][n] = ldsf4(zb + (n * 16 + l15) * 74 + ((ks * 32 + grp * 8) ^ sw));
    }
    ushort* olds = zB + w * 4744;  // overlay (frags already in regs)
    float s4[2][4], q4[2][4];
    #pragma unroll
    for (int m = 0; m < 2; m++)
        #pragma unroll
        for (int r = 0; r < 4; r++) { s4[m][r] = 0.f; q4[m][r] = 0.f; }
    #pragma unroll
    for (int m = 0; m < 2; m++)
        #pragma unroll
        for (int n = 0; n < 4; n++) {
            f32x4 c = {0.f, 0.f, 0.f, 0.f};
            c = mfma16(afr[m][0], bfr[0][n], c);
            c = mfma16(afr[m][1], bfr[1][n], c);
            #pragma unroll
            for (int r = 0; r < 4; r++) {
                float v = c[r];
                s4[m][r] += v; q4[m][r] += v * v;
                olds[(m * 16 + grp * 4 + r) * 64 + n * 16 + l15] = f_to_bf16(v);
            }
        }
    #pragma unroll
    for (int m = 0; m < 2; m++)
        #pragma unroll
        for (int r = 0; r < 4; r++) {
            float sm = s4[m][r], qq = q4[m][r];
            #pragma unroll
            for (int msk = 1; msk <= 8; msk <<= 1) { sm += __shfl_xor(sm, msk); qq += __shfl_xor(qq, msk); }
            if (l15 == 0) {
                int oc = m * 16 + grp * 4 + r;
                atomicAdd(&st3[oc], sm);
                atomicAdd(&st3[32 + oc], qq);
            }
        }
    // o copy (own-wave region, in-order LDS)
    {
        const uint4* ol = (const uint4*)olds;
        uint4* og = (uint4*)(obuf + (size_t)(Pb + w) * 2048);
        #pragma unroll
        for (int kk = 0; kk < 4; kk++) og[l + 64 * kk] = ol[l + 64 * kk];
    }
    __syncthreads();
    if (t < 32) {
        atomicAdd(&ws[SLOTS3  + t * 64 + slot], st3[t]);
        atomicAdd(&ws[SLOTS3Q + t * 64 + slot], st3[32 + t]);
    }
}

// ---------------------------------------------------------------------------
// K4: out = x + bn3(o), vectorized x4.
__global__ __launch_bounds__(NTHREADS)
void k4_read4(const float* __restrict__ x, const float* __restrict__ ws,
              const ushort* __restrict__ obuf, float* __restrict__ out) {
    size_t idx = (size_t)blockIdx.x * NTHREADS + threadIdx.x;
    size_t e = idx * 4;
    int wq = (int)(e & 255);
    int h  = (int)((e >> 8) & 255);
    int oc = (int)((e >> 16) & 31);
    int bi = (int)(e >> 21);
    float a3 = ws[FIN3 + oc], b3c = ws[FIN3 + 32 + oc];
    int blk = (bi << 10) | ((h >> 3) << 5) | (wq >> 3);
    int pix = ((h & 7) << 3) | (wq & 7);
    uint2 ov = *(const uint2*)(obuf + (size_t)blk * 2048 + oc * 64 + pix);
    float4 xv = *(const float4*)(x + e);
    float4 r;
    r.x = xv.x + bf16lo_to_f(ov.x) * a3 + b3c;
    r.y = xv.y + bf16hi_to_f(ov.x) * a3 + b3c;
    r.z = xv.z + bf16lo_to_f(ov.y) * a3 + b3c;
    r.w = xv.w + bf16hi_to_f(ov.y) * a3 + b3c;
    *(float4*)(out + e) = r;
}

__global__ void finalize_k(float* __restrict__ ws, int stage,
                           const float* __restrict__ gamma, const float* __restrict__ beta) {
    int ch = threadIdx.x;
    int nch = (stage == 3) ? 32 : 64;
    if (ch >= nch) return;
    int so = (stage == 1) ? SLOTS1  : (stage == 2) ? SLOTS2  : SLOTS3;
    int sq = (stage == 1) ? SLOTS1Q : (stage == 2) ? SLOTS2Q : SLOTS3Q;
    int fo = (stage == 1) ? FIN1    : (stage == 2) ? FIN2    : FIN3;
    float N = (stage == 1) ? 819200.0f : 524288.0f;
    float sm = 0.f, qq = 0.f;
    for (int j = 0; j < 64; j++) { sm += ws[so + ch*64 + j]; qq += ws[sq + ch*64 + j]; }
    float mean = sm / N;
    float var  = qq / N - mean * mean;
    float rstd = rsqrtf(var + EPSc);
    float a = rstd * gamma[ch];
    ws[fo + ch]       = a;
    ws[fo + nch + ch] = beta[ch] - mean * a;
}

// ---------------------------------------------------------------------------
extern "C" void kernel_launch(void* const* d_in, const int* in_sizes, int n_in,
                              void* d_out, int out_size, void* d_ws, size_t ws_size,
                              hipStream_t stream) {
    const float* x  = (const float*)d_in[0];
    const float* s  = (const float*)d_in[1];
    const float* g1 = (const float*)d_in[2];
    const float* b1 = (const float*)d_in[3];
    const float* g2 = (const float*)d_in[4];
    const float* b2 = (const float*)d_in[5];
    const float* g3 = (const float*)d_in[6];
    const float* b3 = (const float*)d_in[7];
    float* out = (float*)d_out;
    float* ws  = (float*)d_ws;

    hipMemsetAsync(d_ws, 0, STATS_ZERO_FLOATS * sizeof(float), stream);

    ushort* zb = (ushort*)((char*)d_ws + ZB_OFF);
    ushort* ob = (ushort*)((char*)d_ws + OB_OFF);

    k1_mf<<<2048, NTHREADS, 0, stream>>>(x, s, ws);
    finalize_k<<<1, 64, 0, stream>>>(ws, 1, g1, b1);
    k2_mf<<<2048, NTHREADS, 0, stream>>>(x, s, zb, ws);
    finalize_k<<<1, 64, 0, stream>>>(ws, 2, g2, b2);
    k3_mf<<<2048, NTHREADS, 0, stream>>>(zb, s, ob, ws);
    finalize_k<<<1, 64, 0, stream>>>(ws, 3, g3, b3);
    k4_read4<<<16384, NTHREADS, 0, stream>>>(x, ws, ob, out);
}

// Round 8
// 298.779 us; speedup vs baseline: 1.7212x; 1.7212x over previous
//
#include <hip/hip_runtime.h>

#define NT 256

constexpr int R1c = 2048;
constexpr int R2c = 2624;
constexpr float EPSc = 1e-5f;

// ws float offsets (stats)
constexpr int SLOTS1  = 0;
constexpr int SLOTS1Q = 4096;
constexpr int SLOTS2  = 8192;
constexpr int SLOTS2Q = 12288;
constexpr int SLOTS3  = 16384;
constexpr int SLOTS3Q = 18432;
constexpr int FIN1    = 20480;
constexpr int FIN2    = 20608;
constexpr int FIN3    = 20736;
constexpr int STATS_ZERO_FLOATS = 20480;

// ws byte offsets
constexpr size_t ST2_OFF   = 131072;                   // bf16 transposed s
constexpr size_t ST2_BYTES = 8ull * 1024 * 4672 * 2;   // 76,546,048
constexpr size_t ZB_OFF    = ST2_OFF + ST2_BYTES;      // z bf16 [patch][64][64]
constexpr size_t ZB_BYTES  = 8192ull * 4096 * 2;       // 67,108,864
constexpr size_t OI_OFF    = ZB_OFF + ZB_BYTES;        // o bf16 image [bi][32][256][256]

// ---- bf16 helpers -------------------------------------------------------
__device__ __forceinline__ ushort f_to_bf16(float f) {
    union { float f; unsigned int i; } v; v.f = f;
    unsigned int r = (v.i + 0x7fffu + ((v.i >> 16) & 1u)) >> 16;
    return (ushort)r;
}
__device__ __forceinline__ float bf16_to_f(ushort u) {
    union { unsigned int i; float f; } v; v.i = ((unsigned int)u) << 16; return v.f;
}
__device__ __forceinline__ float bf16lo_to_f(unsigned int u) {
    union { unsigned int i; float f; } v; v.i = u << 16; return v.f;
}
__device__ __forceinline__ float bf16hi_to_f(unsigned int u) {
    union { unsigned int i; float f; } v; v.i = u & 0xffff0000u; return v.f;
}
__device__ __forceinline__ unsigned int pack_bf16(float lo, float hi) {
    return (unsigned int)f_to_bf16(lo) | ((unsigned int)f_to_bf16(hi) << 16);
}

typedef short bf16x8 __attribute__((ext_vector_type(8)));
typedef float f32x4  __attribute__((ext_vector_type(4)));
union FR { uint4 u4; bf16x8 v; ushort s[8]; };

__device__ __forceinline__ f32x4 mfma16(bf16x8 a, bf16x8 b, f32x4 c) {
    return __builtin_amdgcn_mfma_f32_16x16x32_bf16(a, b, c, 0, 0, 0);
}

// ---------------------------------------------------------------------------
// Transpose s [8][4672][1024] fp32 -> st bf16 [8][1024][4672] (verified R4/R5)
__global__ __launch_bounds__(256)
void transpose_s_bf16p(const float* __restrict__ s, ushort* __restrict__ st) {
    __shared__ float tile[64][33];
    const int bi = blockIdx.z;
    const int p0 = blockIdx.x * 64;   // 4672 = 73*64
    const int q0 = blockIdx.y * 32;   // 1024 = 32*32
    const int tx = threadIdx.x, ty = threadIdx.y;   // 32 x 8
    const float* sb = s + (size_t)bi * 4672 * 1024;
    #pragma unroll
    for (int r = ty; r < 64; r += 8)
        tile[r][tx] = sb[(size_t)(p0 + r) * 1024 + q0 + tx];
    __syncthreads();
    unsigned int* stu = (unsigned int*)(st + (size_t)bi * 1024 * 4672);
    #pragma unroll
    for (int rr = ty; rr < 32; rr += 8) {
        int q = q0 + rr;
        unsigned int v = pack_bf16(tile[2*tx][rr], tile[2*tx + 1][rr]);
        stu[((size_t)q * 4672 + p0) / 2 + tx] = v;
    }
}

// ---------------------------------------------------------------------------
// Shared staging: block = 4 patches (bi, f, g0..g0+3); wave w owns patch g0+w.
// frB per patch: B-frag layout [n(7)][lane(64)][j(8)] ushort (3584).
// px in [0,112): px=r*10+pc (<100 real), 100..111 zero-padded.

// K1: stats1 only.
__global__ __launch_bounds__(NT, 4)
void k1_mf(const float* __restrict__ x, const ushort* __restrict__ st2,
           float* __restrict__ ws) {
    __shared__ ushort frB[4 * 3584];
    __shared__ float st1[128];
    const int t = threadIdx.x, blk = blockIdx.x;
    const int bi = blk >> 8, f = (blk >> 3) & 31, jb = blk & 7;
    const int g0 = jb * 4, slot = blk & 63;
    const int w = t >> 6, l = t & 63, l15 = l & 15, grp = l >> 4;

    if (t < 128) st1[t] = 0.f;
    {   // zero pad slots: n=6, l15>=4 (px 100..111), all j
        int p = t >> 6, e = t & 63;
        if ((e & 15) >= 4)
            ((uint4*)frB)[p * 448 + 384 + e] = make_uint4(0u, 0u, 0u, 0u);
    }
    // A-frags (w1) direct from global, per wave
    const ushort* wp = st2 + (size_t)(bi * 1024 + f * 32 + g0 + w) * 4672;
    FR aw[4];
    #pragma unroll
    for (int m = 0; m < 4; m++) aw[m].u4 = ((const uint4*)wp)[(m * 16 + l15) * 4 + grp];

    // x staging (float4 rows over 40 cols, reflect halo), scatter to frag layout
    const float* xb = x + (size_t)bi * 32 * 65536;
    for (int i = t; i < 3200; i += NT) {
        int c = i / 100, rem = i - c * 100;
        int r = rem / 10, seg = rem - r * 10;
        int row = f * 8 - 1 + r; row = row < 0 ? -row : (row > 255 ? 510 - row : row);
        int col0 = g0 * 8 - 4 + seg * 4;
        float v4[4];
        if (col0 >= 0 && col0 <= 252) {
            float4 vv = *(const float4*)(xb + (size_t)c * 65536 + row * 256 + col0);
            v4[0] = vv.x; v4[1] = vv.y; v4[2] = vv.z; v4[3] = vv.w;
        } else {
            #pragma unroll
            for (int d = 0; d < 4; d++) {
                int cc = col0 + d; cc = cc < 0 ? -cc : (cc > 255 ? 510 - cc : cc);
                v4[d] = xb[(size_t)c * 65536 + row * 256 + cc];
            }
        }
        int grpc = c >> 3, j = c & 7;
        #pragma unroll
        for (int d = 0; d < 4; d++) {
            int u = col0 + d - g0 * 8;
            ushort hv = f_to_bf16(v4[d]);
            #pragma unroll
            for (int p = 0; p < 4; p++) {
                int pc = u - 8 * p + 1;
                if (pc >= 0 && pc <= 9) {
                    int px = r * 10 + pc;
                    frB[p * 3584 + ((px >> 4) * 64 + grpc * 16 + (px & 15)) * 8 + j] = hv;
                }
            }
        }
    }
    __syncthreads();

    FR b[7];
    const uint4* bp = (const uint4*)(frB + w * 3584);
    #pragma unroll
    for (int n = 0; n < 7; n++) b[n].u4 = bp[n * 64 + l];
    float s4[16], q4[16];
    #pragma unroll
    for (int i = 0; i < 16; i++) { s4[i] = 0.f; q4[i] = 0.f; }
    #pragma unroll
    for (int m = 0; m < 4; m++) {
        #pragma unroll
        for (int n = 0; n < 7; n++) {
            f32x4 z = {0.f, 0.f, 0.f, 0.f};
            f32x4 c = mfma16(aw[m].v, b[n].v, z);
            #pragma unroll
            for (int r = 0; r < 4; r++) { float v = c[r]; s4[m*4+r] += v; q4[m*4+r] += v * v; }
        }
    }
    #pragma unroll
    for (int i = 0; i < 16; i++) {
        float sm = s4[i], qq = q4[i];
        #pragma unroll
        for (int msk = 1; msk <= 8; msk <<= 1) { sm += __shfl_xor(sm, msk); qq += __shfl_xor(qq, msk); }
        if (l15 == 0) {
            int ch = (i >> 2) * 16 + grp * 4 + (i & 3);
            atomicAdd(&st1[ch], sm);
            atomicAdd(&st1[64 + ch], qq);
        }
    }
    __syncthreads();
    if (t < 64) {
        atomicAdd(&ws[SLOTS1  + t * 64 + slot], st1[t]);
        atomicAdd(&ws[SLOTS1Q + t * 64 + slot], st1[64 + t]);
    }
}

// ---------------------------------------------------------------------------
// K2: recompute stage-1 (MFMA), BN1+relu6 -> per-m y slice, depthwise, stats2, z store.
__global__ __launch_bounds__(NT, 3)
void k2_mf(const float* __restrict__ x, const ushort* __restrict__ st2,
           ushort* __restrict__ zbuf, float* __restrict__ ws) {
    __shared__ ushort frB[4 * 3584];
    __shared__ unsigned int w2L[4 * 288];   // FIXED: 288 uints = 576 bf16 per patch
    __shared__ float fin_s[128];
    const int t = threadIdx.x, blk = blockIdx.x;
    const int bi = blk >> 8, f = (blk >> 3) & 31, jb = blk & 7;
    const int g0 = jb * 4, slot = blk & 63;
    const int w = t >> 6, l = t & 63, l15 = l & 15, grp = l >> 4;
    const int patch = bi * 1024 + f * 32 + g0 + w;

    if (t < 128) fin_s[t] = ws[FIN1 + t];
    {
        int p = t >> 6, e = t & 63;
        if ((e & 15) >= 4)
            ((uint4*)frB)[p * 448 + 384 + e] = make_uint4(0u, 0u, 0u, 0u);
    }
    const ushort* wp = st2 + (size_t)patch * 4672;
    FR aw[4];
    #pragma unroll
    for (int m = 0; m < 4; m++) aw[m].u4 = ((const uint4*)wp)[(m * 16 + l15) * 4 + grp];
    for (int k = l; k < 288; k += 64) w2L[w * 288 + k] = ((const unsigned int*)(wp + R1c))[k];

    const float* xb = x + (size_t)bi * 32 * 65536;
    for (int i = t; i < 3200; i += NT) {
        int c = i / 100, rem = i - c * 100;
        int r = rem / 10, seg = rem - r * 10;
        int row = f * 8 - 1 + r; row = row < 0 ? -row : (row > 255 ? 510 - row : row);
        int col0 = g0 * 8 - 4 + seg * 4;
        float v4[4];
        if (col0 >= 0 && col0 <= 252) {
            float4 vv = *(const float4*)(xb + (size_t)c * 65536 + row * 256 + col0);
            v4[0] = vv.x; v4[1] = vv.y; v4[2] = vv.z; v4[3] = vv.w;
        } else {
            #pragma unroll
            for (int d = 0; d < 4; d++) {
                int cc = col0 + d; cc = cc < 0 ? -cc : (cc > 255 ? 510 - cc : cc);
                v4[d] = xb[(size_t)c * 65536 + row * 256 + cc];
            }
        }
        int grpc = c >> 3, j = c & 7;
        #pragma unroll
        for (int d = 0; d < 4; d++) {
            int u = col0 + d - g0 * 8;
            ushort hv = f_to_bf16(v4[d]);
            #pragma unroll
            for (int p = 0; p < 4; p++) {
                int pc = u - 8 * p + 1;
                if (pc >= 0 && pc <= 9) {
                    int px = r * 10 + pc;
                    frB[p * 3584 + ((px >> 4) * 64 + grpc * 16 + (px & 15)) * 8 + j] = hv;
                }
            }
        }
    }
    __syncthreads();

    FR b[7];
    const uint4* bp = (const uint4*)(frB + w * 3584);
    #pragma unroll
    for (int n = 0; n < 7; n++) b[n].u4 = bp[n * 64 + l];

    ushort* slice = frB + w * 3584;        // overlay own patch region (b in regs)
    const ushort* w2u = (const ushort*)(w2L + w * 288);
    const int ch_l = l >> 2, quad = l & 3, p0 = quad * 2;
    float zsum[4], zsq[4];
    ushort* zp0 = zbuf + (size_t)patch * 4096;

    #pragma unroll
    for (int m = 0; m < 4; m++) {
        #pragma unroll
        for (int n = 0; n < 7; n++) {
            f32x4 z = {0.f, 0.f, 0.f, 0.f};
            f32x4 c = mfma16(aw[m].v, b[n].v, z);
            int px = n * 16 + l15;
            if (px < 100) {
                #pragma unroll
                for (int r = 0; r < 4; r++) {
                    int ch = m * 16 + grp * 4 + r;
                    float v = fminf(fmaxf(c[r] * fin_s[ch] + fin_s[64 + ch], 0.f), 6.f);
                    slice[(grp * 4 + r) * 102 + px] = f_to_bf16(v);
                }
            }
        }
        // depthwise 3x3 on this 16-ch slice (lane = channel, quad = row pair)
        float yv[4][10];
        const unsigned int* sl32 = (const unsigned int*)slice;
        #pragma unroll
        for (int rr = 0; rr < 4; rr++) {
            int base = ch_l * 51 + (p0 + rr) * 5;
            #pragma unroll
            for (int k = 0; k < 5; k++) {
                unsigned int u = sl32[base + k];
                yv[rr][2*k] = bf16lo_to_f(u); yv[rr][2*k+1] = bf16hi_to_f(u);
            }
        }
        float wt[9];
        #pragma unroll
        for (int k = 0; k < 9; k++) wt[k] = bf16_to_f(w2u[(m * 16 + ch_l) * 9 + k]);
        float za[2][8];
        #pragma unroll
        for (int rr = 0; rr < 2; rr++)
            #pragma unroll
            for (int q = 0; q < 8; q++) za[rr][q] = 0.f;
        #pragma unroll
        for (int u = 0; u < 3; u++)
            #pragma unroll
            for (int v = 0; v < 3; v++) {
                float wv = wt[u * 3 + v];
                #pragma unroll
                for (int rr = 0; rr < 2; rr++)
                    #pragma unroll
                    for (int q = 0; q < 8; q++)
                        za[rr][q] += wv * yv[rr + u][q + v];
            }
        float zs = 0.f, zq = 0.f;
        #pragma unroll
        for (int rr = 0; rr < 2; rr++)
            #pragma unroll
            for (int q = 0; q < 8; q++) { float v = za[rr][q]; zs += v; zq += v * v; }
        zsum[m] = zs; zsq[m] = zq;
        ushort* zp = zp0 + (m * 16 + ch_l) * 64 + p0 * 8;
        uint4 pk0, pk1;
        pk0.x = pack_bf16(za[0][0], za[0][1]); pk0.y = pack_bf16(za[0][2], za[0][3]);
        pk0.z = pack_bf16(za[0][4], za[0][5]); pk0.w = pack_bf16(za[0][6], za[0][7]);
        pk1.x = pack_bf16(za[1][0], za[1][1]); pk1.y = pack_bf16(za[1][2], za[1][3]);
        pk1.z = pack_bf16(za[1][4], za[1][5]); pk1.w = pack_bf16(za[1][6], za[1][7]);
        *(uint4*)zp = pk0;
        *(uint4*)(zp + 8) = pk1;
    }
    __syncthreads();
    if (t < 128) fin_s[t] = 0.f;   // reuse as stats2 accumulator
    __syncthreads();
    #pragma unroll
    for (int m = 0; m < 4; m++) {
        float zs = zsum[m], zq = zsq[m];
        zs += __shfl_xor(zs, 1); zs += __shfl_xor(zs, 2);
        zq += __shfl_xor(zq, 1); zq += __shfl_xor(zq, 2);
        if (quad == 0) {
            atomicAdd(&fin_s[m * 16 + ch_l], zs);
            atomicAdd(&fin_s[64 + m * 16 + ch_l], zq);
        }
    }
    __syncthreads();
    if (t < 64) {
        atomicAdd(&ws[SLOTS2  + t * 64 + slot], fin_s[t]);
        atomicAdd(&ws[SLOTS2Q + t * 64 + slot], fin_s[64 + t]);
    }
}

// ---------------------------------------------------------------------------
// K3: z -> BN2+relu6 -> MFMA (M=32,N=64,K=64) -> stats3 + o image store.
__global__ __launch_bounds__(NT, 4)
void k3_mf(const ushort* __restrict__ zbuf, const ushort* __restrict__ st2,
           ushort* __restrict__ oi, float* __restrict__ ws) {
    __shared__ ushort zL[4 * 4224];     // per patch [64 ch][66]
    __shared__ float fin2[128];
    __shared__ float st3[64];
    const int t = threadIdx.x, blk = blockIdx.x;
    const int bi = blk >> 8, f = (blk >> 3) & 31, jb = blk & 7;
    const int g0 = jb * 4, slot = blk & 63;
    const int w = t >> 6, l = t & 63, l15 = l & 15, grp = l >> 4;
    const int patch = bi * 1024 + f * 32 + g0 + w;

    if (t < 128) fin2[t] = ws[FIN2 + t];
    if (t >= 128 && t < 192) st3[t - 128] = 0.f;
    const ushort* wp = st2 + (size_t)patch * 4672;
    FR aw[2][2];
    #pragma unroll
    for (int m = 0; m < 2; m++)
        #pragma unroll
        for (int ks = 0; ks < 2; ks++)
            aw[m][ks].u4 = ((const uint4*)(wp + R2c))[(m * 16 + l15) * 8 + ks * 4 + grp];
    __syncthreads();   // fin2 ready

    // stage z (wave-local): BN2+relu6, [ch][66] padded rows
    const uint4* zsrc = (const uint4*)(zbuf + (size_t)patch * 4096);
    unsigned int* zd = (unsigned int*)zL;
    #pragma unroll
    for (int it = 0; it < 8; it++) {
        int i = l + 64 * it;
        uint4 v = zsrc[i];
        int ch = i >> 3, px0 = (i & 7) * 8;
        float a2 = fin2[ch], b2 = fin2[64 + ch];
        unsigned int uu[4] = {v.x, v.y, v.z, v.w};
        int base = w * 2112 + (ch * 66 + px0) / 2;
        #pragma unroll
        for (int k = 0; k < 4; k++) {
            float lo = fminf(fmaxf(bf16lo_to_f(uu[k]) * a2 + b2, 0.f), 6.f);
            float hi = fminf(fmaxf(bf16hi_to_f(uu[k]) * a2 + b2, 0.f), 6.f);
            zd[base + k] = pack_bf16(lo, hi);
        }
    }
    // B-frags (wave-local LDS, in-order)
    FR bfr[2][4];
    #pragma unroll
    for (int ks = 0; ks < 2; ks++)
        #pragma unroll
        for (int n = 0; n < 4; n++)
            #pragma unroll
            for (int j = 0; j < 8; j++)
                bfr[ks][n].s[j] = zL[w * 4224 + (ks * 32 + grp * 8 + j) * 66 + n * 16 + l15];

    float s4[2][4], q4[2][4];
    #pragma unroll
    for (int m = 0; m < 2; m++)
        #pragma unroll
        for (int r = 0; r < 4; r++) { s4[m][r] = 0.f; q4[m][r] = 0.f; }
    #pragma unroll
    for (int m = 0; m < 2; m++)
        #pragma unroll
        for (int n = 0; n < 4; n++) {
            f32x4 z = {0.f, 0.f, 0.f, 0.f};
            f32x4 c = mfma16(aw[m][0].v, bfr[0][n].v, z);
            c = mfma16(aw[m][1].v, bfr[1][n].v, c);
            #pragma unroll
            for (int r = 0; r < 4; r++) {
                float v = c[r];
                s4[m][r] += v; q4[m][r] += v * v;
                int oc = m * 16 + grp * 4 + r;
                int px = n * 16 + l15, p = px >> 3, q = px & 7;
                oi[((size_t)(bi * 32 + oc) * 256 + f * 8 + p) * 256 + (g0 + w) * 8 + q] = f_to_bf16(v);
            }
        }
    #pragma unroll
    for (int m = 0; m < 2; m++)
        #pragma unroll
        for (int r = 0; r < 4; r++) {
            float sm = s4[m][r], qq = q4[m][r];
            #pragma unroll
            for (int msk = 1; msk <= 8; msk <<= 1) { sm += __shfl_xor(sm, msk); qq += __shfl_xor(qq, msk); }
            if (l15 == 0) {
                int oc = m * 16 + grp * 4 + r;
                atomicAdd(&st3[oc], sm);
                atomicAdd(&st3[32 + oc], qq);
            }
        }
    __syncthreads();
    if (t < 32) {
        atomicAdd(&ws[SLOTS3  + t * 64 + slot], st3[t]);
        atomicAdd(&ws[SLOTS3Q + t * 64 + slot], st3[32 + t]);
    }
}

// ---------------------------------------------------------------------------
// K4: out = x + bn3(o), pure float4 stream (o in image layout).
__global__ __launch_bounds__(NT, 8)
void k4_st(const float* __restrict__ x, const float* __restrict__ ws,
           const ushort* __restrict__ oi, float* __restrict__ out) {
    #pragma unroll
    for (int it = 0; it < 8; it++) {
        size_t e = ((size_t)(blockIdx.x * NT + threadIdx.x) + (size_t)it * (2048 * NT)) * 4;
        int oc = (int)((e >> 16) & 31);
        float a3 = ws[FIN3 + oc], b3 = ws[FIN3 + 32 + oc];
        uint2 ov = *(const uint2*)(oi + e);
        float4 xv = *(const float4*)(x + e);
        float4 r;
        r.x = xv.x + bf16lo_to_f(ov.x) * a3 + b3;
        r.y = xv.y + bf16hi_to_f(ov.x) * a3 + b3;
        r.z = xv.z + bf16lo_to_f(ov.y) * a3 + b3;
        r.w = xv.w + bf16hi_to_f(ov.y) * a3 + b3;
        *(float4*)(out + e) = r;
    }
}

__global__ void finalize_k(float* __restrict__ ws, int stage,
                           const float* __restrict__ gamma, const float* __restrict__ beta) {
    int ch = threadIdx.x;
    int nch = (stage == 3) ? 32 : 64;
    if (ch >= nch) return;
    int so = (stage == 1) ? SLOTS1  : (stage == 2) ? SLOTS2  : SLOTS3;
    int sq = (stage == 1) ? SLOTS1Q : (stage == 2) ? SLOTS2Q : SLOTS3Q;
    int fo = (stage == 1) ? FIN1    : (stage == 2) ? FIN2    : FIN3;
    float N = (stage == 1) ? 819200.0f : 524288.0f;
    float sm = 0.f, qq = 0.f;
    for (int j = 0; j < 64; j++) { sm += ws[so + ch*64 + j]; qq += ws[sq + ch*64 + j]; }
    float mean = sm / N;
    float var  = qq / N - mean * mean;
    float rstd = rsqrtf(var + EPSc);
    float a = rstd * gamma[ch];
    ws[fo + ch]       = a;
    ws[fo + nch + ch] = beta[ch] - mean * a;
}

// ---------------------------------------------------------------------------
extern "C" void kernel_launch(void* const* d_in, const int* in_sizes, int n_in,
                              void* d_out, int out_size, void* d_ws, size_t ws_size,
                              hipStream_t stream) {
    const float* x  = (const float*)d_in[0];
    const float* s  = (const float*)d_in[1];
    const float* g1 = (const float*)d_in[2];
    const float* b1 = (const float*)d_in[3];
    const float* g2 = (const float*)d_in[4];
    const float* b2 = (const float*)d_in[5];
    const float* g3 = (const float*)d_in[6];
    const float* b3 = (const float*)d_in[7];
    float* out = (float*)d_out;
    float* ws  = (float*)d_ws;

    hipMemsetAsync(d_ws, 0, STATS_ZERO_FLOATS * sizeof(float), stream);

    ushort* st2 = (ushort*)((char*)d_ws + ST2_OFF);
    ushort* zb  = (ushort*)((char*)d_ws + ZB_OFF);
    ushort* oi  = (ushort*)((char*)d_ws + OI_OFF);

    transpose_s_bf16p<<<dim3(73, 32, 8), dim3(32, 8), 0, stream>>>(s, st2);
    k1_mf<<<2048, NT, 0, stream>>>(x, st2, ws);
    finalize_k<<<1, 64, 0, stream>>>(ws, 1, g1, b1);
    k2_mf<<<2048, NT, 0, stream>>>(x, st2, zb, ws);
    finalize_k<<<1, 64, 0, stream>>>(ws, 2, g2, b2);
    k3_mf<<<2048, NT, 0, stream>>>(zb, st2, oi, ws);
    finalize_k<<<1, 64, 0, stream>>>(ws, 3, g3, b3);
    k4_st<<<2048, NT, 0, stream>>>(x, ws, oi, out);
}

// Round 9
// 284.779 us; speedup vs baseline: 1.8058x; 1.0492x over previous
//
#include <hip/hip_runtime.h>

#define NT 256

constexpr int R1c = 2048;
constexpr int R2c = 2624;
constexpr float EPSc = 1e-5f;

// ws float offsets (stats)
constexpr int SLOTS1  = 0;
constexpr int SLOTS1Q = 4096;
constexpr int SLOTS2  = 8192;
constexpr int SLOTS2Q = 12288;
constexpr int SLOTS3  = 16384;
constexpr int SLOTS3Q = 18432;
constexpr int FIN1    = 20480;
constexpr int FIN2    = 20608;
constexpr int FIN3    = 20736;
constexpr int STATS_ZERO_FLOATS = 20480;

// ws byte offsets
constexpr size_t ST2_OFF   = 131072;                   // bf16 transposed s
constexpr size_t ST2_BYTES = 8ull * 1024 * 4672 * 2;   // 76,546,048
constexpr size_t ZB_OFF    = ST2_OFF + ST2_BYTES;      // z bf16 [patch][64][64]
constexpr size_t ZB_BYTES  = 8192ull * 4096 * 2;       // 67,108,864
constexpr size_t Y_OFF     = ZB_OFF + ZB_BYTES;        // 143,785,984
constexpr size_t Y_BYTES   = 8192ull * 13312;          // y bf16 [patch][64][104]
constexpr size_t NEED_Y    = Y_OFF + Y_BYTES;          // 252,837,888
constexpr size_t OI_OFF    = Y_OFF;                    // o image overlays dead y (both paths)

// ---- bf16 helpers -------------------------------------------------------
__device__ __forceinline__ ushort f_to_bf16(float f) {
    union { float f; unsigned int i; } v; v.f = f;
    unsigned int r = (v.i + 0x7fffu + ((v.i >> 16) & 1u)) >> 16;
    return (ushort)r;
}
__device__ __forceinline__ float bf16_to_f(ushort u) {
    union { unsigned int i; float f; } v; v.i = ((unsigned int)u) << 16; return v.f;
}
__device__ __forceinline__ float bf16lo_to_f(unsigned int u) {
    union { unsigned int i; float f; } v; v.i = u << 16; return v.f;
}
__device__ __forceinline__ float bf16hi_to_f(unsigned int u) {
    union { unsigned int i; float f; } v; v.i = u & 0xffff0000u; return v.f;
}
__device__ __forceinline__ unsigned int pack_bf16(float lo, float hi) {
    return (unsigned int)f_to_bf16(lo) | ((unsigned int)f_to_bf16(hi) << 16);
}

typedef short bf16x8 __attribute__((ext_vector_type(8)));
typedef float f32x4  __attribute__((ext_vector_type(4)));
union FR { uint4 u4; bf16x8 v; ushort s[8]; };

__device__ __forceinline__ f32x4 mfma16(bf16x8 a, bf16x8 b, f32x4 c) {
    return __builtin_amdgcn_mfma_f32_16x16x32_bf16(a, b, c, 0, 0, 0);
}

// ---------------------------------------------------------------------------
// Transpose s [8][4672][1024] fp32 -> st bf16 [8][1024][4672]
__global__ __launch_bounds__(256)
void transpose_s_bf16p(const float* __restrict__ s, ushort* __restrict__ st) {
    __shared__ float tile[64][33];
    const int bi = blockIdx.z;
    const int p0 = blockIdx.x * 64;
    const int q0 = blockIdx.y * 32;
    const int tx = threadIdx.x, ty = threadIdx.y;
    const float* sb = s + (size_t)bi * 4672 * 1024;
    #pragma unroll
    for (int r = ty; r < 64; r += 8)
        tile[r][tx] = sb[(size_t)(p0 + r) * 1024 + q0 + tx];
    __syncthreads();
    unsigned int* stu = (unsigned int*)(st + (size_t)bi * 1024 * 4672);
    #pragma unroll
    for (int rr = ty; rr < 32; rr += 8) {
        int q = q0 + rr;
        unsigned int v = pack_bf16(tile[2*tx][rr], tile[2*tx + 1][rr]);
        stu[((size_t)q * 4672 + p0) / 2 + tx] = v;
    }
}

// ---------------------------------------------------------------------------
// K1: stage-1 MFMA + stats1; SY=1 additionally streams raw y bf16 to ybuf
//     [patch][64 ch][104 px] via an LDS slice bounce (coalesced uint4 out).
template<int SY>
__global__ __launch_bounds__(NT, 4)
void k1_mf(const float* __restrict__ x, const ushort* __restrict__ st2,
           ushort* __restrict__ ybuf, float* __restrict__ ws) {
    __shared__ ushort frB[4 * 3584];
    __shared__ float st1[128];
    const int t = threadIdx.x, blk = blockIdx.x;
    const int bi = blk >> 8, f = (blk >> 3) & 31, jb = blk & 7;
    const int g0 = jb * 4, slot = blk & 63;
    const int w = t >> 6, l = t & 63, l15 = l & 15, grp = l >> 4;
    const int patch = bi * 1024 + f * 32 + g0 + w;

    if (t < 128) st1[t] = 0.f;
    {   // zero pad slots: n=6, l15>=4 (px 100..111), all j
        int p = t >> 6, e = t & 63;
        if ((e & 15) >= 4)
            ((uint4*)frB)[p * 448 + 384 + e] = make_uint4(0u, 0u, 0u, 0u);
    }
    const ushort* wp = st2 + (size_t)patch * 4672;
    FR aw[4];
    #pragma unroll
    for (int m = 0; m < 4; m++) aw[m].u4 = ((const uint4*)wp)[(m * 16 + l15) * 4 + grp];

    const float* xb = x + (size_t)bi * 32 * 65536;
    for (int i = t; i < 3200; i += NT) {
        int c = i / 100, rem = i - c * 100;
        int r = rem / 10, seg = rem - r * 10;
        int row = f * 8 - 1 + r; row = row < 0 ? -row : (row > 255 ? 510 - row : row);
        int col0 = g0 * 8 - 4 + seg * 4;
        float v4[4];
        if (col0 >= 0 && col0 <= 252) {
            float4 vv = *(const float4*)(xb + (size_t)c * 65536 + row * 256 + col0);
            v4[0] = vv.x; v4[1] = vv.y; v4[2] = vv.z; v4[3] = vv.w;
        } else {
            #pragma unroll
            for (int d = 0; d < 4; d++) {
                int cc = col0 + d; cc = cc < 0 ? -cc : (cc > 255 ? 510 - cc : cc);
                v4[d] = xb[(size_t)c * 65536 + row * 256 + cc];
            }
        }
        int grpc = c >> 3, j = c & 7;
        #pragma unroll
        for (int d = 0; d < 4; d++) {
            int u = col0 + d - g0 * 8;
            ushort hv = f_to_bf16(v4[d]);
            #pragma unroll
            for (int p = 0; p < 4; p++) {
                int pc = u - 8 * p + 1;
                if (pc >= 0 && pc <= 9) {
                    int px = r * 10 + pc;
                    frB[p * 3584 + ((px >> 4) * 64 + grpc * 16 + (px & 15)) * 8 + j] = hv;
                }
            }
        }
    }
    __syncthreads();

    FR b[7];
    const uint4* bp = (const uint4*)(frB + w * 3584);
    #pragma unroll
    for (int n = 0; n < 7; n++) b[n].u4 = bp[n * 64 + l];

    ushort* slice = frB + w * 3584;                 // overlay own region ([16][106])
    unsigned int* sliceU = (unsigned int*)slice;
    uint4* yb4 = SY ? (((uint4*)ybuf) + (size_t)patch * 832) : nullptr;

    float s4[16], q4[16];
    #pragma unroll
    for (int i = 0; i < 16; i++) { s4[i] = 0.f; q4[i] = 0.f; }
    #pragma unroll
    for (int m = 0; m < 4; m++) {
        #pragma unroll
        for (int n = 0; n < 7; n++) {
            f32x4 z = {0.f, 0.f, 0.f, 0.f};
            f32x4 c = mfma16(aw[m].v, b[n].v, z);
            int px = n * 16 + l15;
            #pragma unroll
            for (int r = 0; r < 4; r++) {
                float v = c[r]; s4[m*4+r] += v; q4[m*4+r] += v * v;
                if (SY && px < 100) slice[(grp * 4 + r) * 106 + px] = f_to_bf16(v);
            }
        }
        if (SY) {
            for (int i = l; i < 208; i += 64) {
                int ch2 = i / 13, sub = i - ch2 * 13;
                int ub = ch2 * 53 + sub * 4;
                yb4[m * 208 + i] = make_uint4(sliceU[ub], sliceU[ub+1], sliceU[ub+2], sliceU[ub+3]);
            }
        }
    }
    #pragma unroll
    for (int i = 0; i < 16; i++) {
        float sm = s4[i], qq = q4[i];
        #pragma unroll
        for (int msk = 1; msk <= 8; msk <<= 1) { sm += __shfl_xor(sm, msk); qq += __shfl_xor(qq, msk); }
        if (l15 == 0) {
            int ch = (i >> 2) * 16 + grp * 4 + (i & 3);
            atomicAdd(&st1[ch], sm);
            atomicAdd(&st1[64 + ch], qq);
        }
    }
    __syncthreads();
    if (t < 64) {
        atomicAdd(&ws[SLOTS1  + t * 64 + slot], st1[t]);
        atomicAdd(&ws[SLOTS1Q + t * 64 + slot], st1[64 + t]);
    }
}

// ---------------------------------------------------------------------------
// K2 (fast path): read y bf16 coalesced, BN1+relu6 on unpack, depthwise 3x3,
// stats2, store z bf16. No stage-1 recompute. LDS ~19 KB.
__global__ __launch_bounds__(NT, 4)
void k2_y(const ushort* __restrict__ ybuf, const ushort* __restrict__ st2,
          ushort* __restrict__ zbuf, float* __restrict__ ws) {
    __shared__ ushort slc[4 * 1696];       // per wave [16 ch][106]
    __shared__ unsigned int w2L[4 * 288];
    __shared__ float fin_s[128];
    const int t = threadIdx.x, blk = blockIdx.x;
    const int bi = blk >> 8, f = (blk >> 3) & 31, jb = blk & 7;
    const int g0 = jb * 4, slot = blk & 63;
    const int w = t >> 6, l = t & 63;
    const int ch_l = l >> 2, quad = l & 3, p0 = quad * 2;
    const int patch = bi * 1024 + f * 32 + g0 + w;

    if (t < 128) fin_s[t] = ws[FIN1 + t];
    const ushort* wp = st2 + (size_t)patch * 4672;
    for (int k = l; k < 288; k += 64) w2L[w * 288 + k] = ((const unsigned int*)(wp + R1c))[k];
    __syncthreads();

    const uint4* yb4 = ((const uint4*)ybuf) + (size_t)patch * 832;
    ushort* slice = slc + w * 1696;
    unsigned int* sliceU = (unsigned int*)slice;
    const ushort* w2u = (const ushort*)(w2L + w * 288);
    ushort* zp0 = zbuf + (size_t)patch * 4096;
    float zsum[4], zsq[4];

    #pragma unroll
    for (int m = 0; m < 4; m++) {
        for (int i = l; i < 208; i += 64) {
            uint4 v = yb4[m * 208 + i];
            int ch2 = i / 13, sub = i - ch2 * 13;
            int ch = m * 16 + ch2;
            float a1 = fin_s[ch], b1 = fin_s[64 + ch];
            unsigned int uu[4] = {v.x, v.y, v.z, v.w};
            int ub = ch2 * 53 + sub * 4;
            #pragma unroll
            for (int k = 0; k < 4; k++) {
                float lo = fminf(fmaxf(bf16lo_to_f(uu[k]) * a1 + b1, 0.f), 6.f);
                float hi = fminf(fmaxf(bf16hi_to_f(uu[k]) * a1 + b1, 0.f), 6.f);
                sliceU[ub + k] = pack_bf16(lo, hi);
            }
        }
        // depthwise 3x3 (wave-local LDS, program order)
        float yv[4][10];
        #pragma unroll
        for (int rr = 0; rr < 4; rr++) {
            int base = ch_l * 53 + (p0 + rr) * 5;
            #pragma unroll
            for (int k = 0; k < 5; k++) {
                unsigned int u = sliceU[base + k];
                yv[rr][2*k] = bf16lo_to_f(u); yv[rr][2*k+1] = bf16hi_to_f(u);
            }
        }
        float wt[9];
        #pragma unroll
        for (int k = 0; k < 9; k++) wt[k] = bf16_to_f(w2u[(m * 16 + ch_l) * 9 + k]);
        float za[2][8];
        #pragma unroll
        for (int rr = 0; rr < 2; rr++)
            #pragma unroll
            for (int q = 0; q < 8; q++) za[rr][q] = 0.f;
        #pragma unroll
        for (int u = 0; u < 3; u++)
            #pragma unroll
            for (int v = 0; v < 3; v++) {
                float wv = wt[u * 3 + v];
                #pragma unroll
                for (int rr = 0; rr < 2; rr++)
                    #pragma unroll
                    for (int q = 0; q < 8; q++)
                        za[rr][q] += wv * yv[rr + u][q + v];
            }
        float zs = 0.f, zq = 0.f;
        #pragma unroll
        for (int rr = 0; rr < 2; rr++)
            #pragma unroll
            for (int q = 0; q < 8; q++) { float v = za[rr][q]; zs += v; zq += v * v; }
        zsum[m] = zs; zsq[m] = zq;
        ushort* zp = zp0 + (m * 16 + ch_l) * 64 + p0 * 8;
        uint4 pk0, pk1;
        pk0.x = pack_bf16(za[0][0], za[0][1]); pk0.y = pack_bf16(za[0][2], za[0][3]);
        pk0.z = pack_bf16(za[0][4], za[0][5]); pk0.w = pack_bf16(za[0][6], za[0][7]);
        pk1.x = pack_bf16(za[1][0], za[1][1]); pk1.y = pack_bf16(za[1][2], za[1][3]);
        pk1.z = pack_bf16(za[1][4], za[1][5]); pk1.w = pack_bf16(za[1][6], za[1][7]);
        *(uint4*)zp = pk0;
        *(uint4*)(zp + 8) = pk1;
    }
    __syncthreads();
    if (t < 128) fin_s[t] = 0.f;   // reuse as stats2 accumulator
    __syncthreads();
    #pragma unroll
    for (int m = 0; m < 4; m++) {
        float zs = zsum[m], zq = zsq[m];
        zs += __shfl_xor(zs, 1); zs += __shfl_xor(zs, 2);
        zq += __shfl_xor(zq, 1); zq += __shfl_xor(zq, 2);
        if (quad == 0) {
            atomicAdd(&fin_s[m * 16 + ch_l], zs);
            atomicAdd(&fin_s[64 + m * 16 + ch_l], zq);
        }
    }
    __syncthreads();
    if (t < 64) {
        atomicAdd(&ws[SLOTS2  + t * 64 + slot], fin_s[t]);
        atomicAdd(&ws[SLOTS2Q + t * 64 + slot], fin_s[64 + t]);
    }
}

// ---------------------------------------------------------------------------
// K2 (fallback, R8): recompute stage-1 (MFMA), BN1+relu6, depthwise, stats2, z.
__global__ __launch_bounds__(NT, 3)
void k2_mf(const float* __restrict__ x, const ushort* __restrict__ st2,
           ushort* __restrict__ zbuf, float* __restrict__ ws) {
    __shared__ ushort frB[4 * 3584];
    __shared__ unsigned int w2L[4 * 288];
    __shared__ float fin_s[128];
    const int t = threadIdx.x, blk = blockIdx.x;
    const int bi = blk >> 8, f = (blk >> 3) & 31, jb = blk & 7;
    const int g0 = jb * 4, slot = blk & 63;
    const int w = t >> 6, l = t & 63, l15 = l & 15, grp = l >> 4;
    const int patch = bi * 1024 + f * 32 + g0 + w;

    if (t < 128) fin_s[t] = ws[FIN1 + t];
    {
        int p = t >> 6, e = t & 63;
        if ((e & 15) >= 4)
            ((uint4*)frB)[p * 448 + 384 + e] = make_uint4(0u, 0u, 0u, 0u);
    }
    const ushort* wp = st2 + (size_t)patch * 4672;
    FR aw[4];
    #pragma unroll
    for (int m = 0; m < 4; m++) aw[m].u4 = ((const uint4*)wp)[(m * 16 + l15) * 4 + grp];
    for (int k = l; k < 288; k += 64) w2L[w * 288 + k] = ((const unsigned int*)(wp + R1c))[k];

    const float* xb = x + (size_t)bi * 32 * 65536;
    for (int i = t; i < 3200; i += NT) {
        int c = i / 100, rem = i - c * 100;
        int r = rem / 10, seg = rem - r * 10;
        int row = f * 8 - 1 + r; row = row < 0 ? -row : (row > 255 ? 510 - row : row);
        int col0 = g0 * 8 - 4 + seg * 4;
        float v4[4];
        if (col0 >= 0 && col0 <= 252) {
            float4 vv = *(const float4*)(xb + (size_t)c * 65536 + row * 256 + col0);
            v4[0] = vv.x; v4[1] = vv.y; v4[2] = vv.z; v4[3] = vv.w;
        } else {
            #pragma unroll
            for (int d = 0; d < 4; d++) {
                int cc = col0 + d; cc = cc < 0 ? -cc : (cc > 255 ? 510 - cc : cc);
                v4[d] = xb[(size_t)c * 65536 + row * 256 + cc];
            }
        }
        int grpc = c >> 3, j = c & 7;
        #pragma unroll
        for (int d = 0; d < 4; d++) {
            int u = col0 + d - g0 * 8;
            ushort hv = f_to_bf16(v4[d]);
            #pragma unroll
            for (int p = 0; p < 4; p++) {
                int pc = u - 8 * p + 1;
                if (pc >= 0 && pc <= 9) {
                    int px = r * 10 + pc;
                    frB[p * 3584 + ((px >> 4) * 64 + grpc * 16 + (px & 15)) * 8 + j] = hv;
                }
            }
        }
    }
    __syncthreads();

    FR b[7];
    const uint4* bp = (const uint4*)(frB + w * 3584);
    #pragma unroll
    for (int n = 0; n < 7; n++) b[n].u4 = bp[n * 64 + l];

    ushort* slice = frB + w * 3584;
    const ushort* w2u = (const ushort*)(w2L + w * 288);
    const int ch_l = l >> 2, quad = l & 3, p0 = quad * 2;
    float zsum[4], zsq[4];
    ushort* zp0 = zbuf + (size_t)patch * 4096;

    #pragma unroll
    for (int m = 0; m < 4; m++) {
        #pragma unroll
        for (int n = 0; n < 7; n++) {
            f32x4 z = {0.f, 0.f, 0.f, 0.f};
            f32x4 c = mfma16(aw[m].v, b[n].v, z);
            int px = n * 16 + l15;
            if (px < 100) {
                #pragma unroll
                for (int r = 0; r < 4; r++) {
                    int ch = m * 16 + grp * 4 + r;
                    float v = fminf(fmaxf(c[r] * fin_s[ch] + fin_s[64 + ch], 0.f), 6.f);
                    slice[(grp * 4 + r) * 102 + px] = f_to_bf16(v);
                }
            }
        }
        float yv[4][10];
        const unsigned int* sl32 = (const unsigned int*)slice;
        #pragma unroll
        for (int rr = 0; rr < 4; rr++) {
            int base = ch_l * 51 + (p0 + rr) * 5;
            #pragma unroll
            for (int k = 0; k < 5; k++) {
                unsigned int u = sl32[base + k];
                yv[rr][2*k] = bf16lo_to_f(u); yv[rr][2*k+1] = bf16hi_to_f(u);
            }
        }
        float wt[9];
        #pragma unroll
        for (int k = 0; k < 9; k++) wt[k] = bf16_to_f(w2u[(m * 16 + ch_l) * 9 + k]);
        float za[2][8];
        #pragma unroll
        for (int rr = 0; rr < 2; rr++)
            #pragma unroll
            for (int q = 0; q < 8; q++) za[rr][q] = 0.f;
        #pragma unroll
        for (int u = 0; u < 3; u++)
            #pragma unroll
            for (int v = 0; v < 3; v++) {
                float wv = wt[u * 3 + v];
                #pragma unroll
                for (int rr = 0; rr < 2; rr++)
                    #pragma unroll
                    for (int q = 0; q < 8; q++)
                        za[rr][q] += wv * yv[rr + u][q + v];
            }
        float zs = 0.f, zq = 0.f;
        #pragma unroll
        for (int rr = 0; rr < 2; rr++)
            #pragma unroll
            for (int q = 0; q < 8; q++) { float v = za[rr][q]; zs += v; zq += v * v; }
        zsum[m] = zs; zsq[m] = zq;
        ushort* zp = zp0 + (m * 16 + ch_l) * 64 + p0 * 8;
        uint4 pk0, pk1;
        pk0.x = pack_bf16(za[0][0], za[0][1]); pk0.y = pack_bf16(za[0][2], za[0][3]);
        pk0.z = pack_bf16(za[0][4], za[0][5]); pk0.w = pack_bf16(za[0][6], za[0][7]);
        pk1.x = pack_bf16(za[1][0], za[1][1]); pk1.y = pack_bf16(za[1][2], za[1][3]);
        pk1.z = pack_bf16(za[1][4], za[1][5]); pk1.w = pack_bf16(za[1][6], za[1][7]);
        *(uint4*)zp = pk0;
        *(uint4*)(zp + 8) = pk1;
    }
    __syncthreads();
    if (t < 128) fin_s[t] = 0.f;
    __syncthreads();
    #pragma unroll
    for (int m = 0; m < 4; m++) {
        float zs = zsum[m], zq = zsq[m];
        zs += __shfl_xor(zs, 1); zs += __shfl_xor(zs, 2);
        zq += __shfl_xor(zq, 1); zq += __shfl_xor(zq, 2);
        if (quad == 0) {
            atomicAdd(&fin_s[m * 16 + ch_l], zs);
            atomicAdd(&fin_s[64 + m * 16 + ch_l], zq);
        }
    }
    __syncthreads();
    if (t < 64) {
        atomicAdd(&ws[SLOTS2  + t * 64 + slot], fin_s[t]);
        atomicAdd(&ws[SLOTS2Q + t * 64 + slot], fin_s[64 + t]);
    }
}

// ---------------------------------------------------------------------------
// K3: z -> BN2+relu6 -> MFMA (M=32,N=64,K=64) -> stats3 + o image store.
__global__ __launch_bounds__(NT, 4)
void k3_mf(const ushort* __restrict__ zbuf, const ushort* __restrict__ st2,
           ushort* __restrict__ oi, float* __restrict__ ws) {
    __shared__ ushort zL[4 * 4224];     // per patch [64 ch][66]
    __shared__ float fin2[128];
    __shared__ float st3[64];
    const int t = threadIdx.x, blk = blockIdx.x;
    const int bi = blk >> 8, f = (blk >> 3) & 31, jb = blk & 7;
    const int g0 = jb * 4, slot = blk & 63;
    const int w = t >> 6, l = t & 63, l15 = l & 15, grp = l >> 4;
    const int patch = bi * 1024 + f * 32 + g0 + w;

    if (t < 128) fin2[t] = ws[FIN2 + t];
    if (t >= 128 && t < 192) st3[t - 128] = 0.f;
    const ushort* wp = st2 + (size_t)patch * 4672;
    FR aw[2][2];
    #pragma unroll
    for (int m = 0; m < 2; m++)
        #pragma unroll
        for (int ks = 0; ks < 2; ks++)
            aw[m][ks].u4 = ((const uint4*)(wp + R2c))[(m * 16 + l15) * 8 + ks * 4 + grp];
    __syncthreads();   // fin2 ready

    const uint4* zsrc = (const uint4*)(zbuf + (size_t)patch * 4096);
    unsigned int* zd = (unsigned int*)zL;
    #pragma unroll
    for (int it = 0; it < 8; it++) {
        int i = l + 64 * it;
        uint4 v = zsrc[i];
        int ch = i >> 3, px0 = (i & 7) * 8;
        float a2 = fin2[ch], b2 = fin2[64 + ch];
        unsigned int uu[4] = {v.x, v.y, v.z, v.w};
        int base = w * 2112 + (ch * 66 + px0) / 2;
        #pragma unroll
        for (int k = 0; k < 4; k++) {
            float lo = fminf(fmaxf(bf16lo_to_f(uu[k]) * a2 + b2, 0.f), 6.f);
            float hi = fminf(fmaxf(bf16hi_to_f(uu[k]) * a2 + b2, 0.f), 6.f);
            zd[base + k] = pack_bf16(lo, hi);
        }
    }
    FR bfr[2][4];
    #pragma unroll
    for (int ks = 0; ks < 2; ks++)
        #pragma unroll
        for (int n = 0; n < 4; n++)
            #pragma unroll
            for (int j = 0; j < 8; j++)
                bfr[ks][n].s[j] = zL[w * 4224 + (ks * 32 + grp * 8 + j) * 66 + n * 16 + l15];

    float s4[2][4], q4[2][4];
    #pragma unroll
    for (int m = 0; m < 2; m++)
        #pragma unroll
        for (int r = 0; r < 4; r++) { s4[m][r] = 0.f; q4[m][r] = 0.f; }
    #pragma unroll
    for (int m = 0; m < 2; m++)
        #pragma unroll
        for (int n = 0; n < 4; n++) {
            f32x4 z = {0.f, 0.f, 0.f, 0.f};
            f32x4 c = mfma16(aw[m][0].v, bfr[0][n].v, z);
            c = mfma16(aw[m][1].v, bfr[1][n].v, c);
            #pragma unroll
            for (int r = 0; r < 4; r++) {
                float v = c[r];
                s4[m][r] += v; q4[m][r] += v * v;
                int oc = m * 16 + grp * 4 + r;
                int px = n * 16 + l15, p = px >> 3, q = px & 7;
                oi[((size_t)(bi * 32 + oc) * 256 + f * 8 + p) * 256 + (g0 + w) * 8 + q] = f_to_bf16(v);
            }
        }
    #pragma unroll
    for (int m = 0; m < 2; m++)
        #pragma unroll
        for (int r = 0; r < 4; r++) {
            float sm = s4[m][r], qq = q4[m][r];
            #pragma unroll
            for (int msk = 1; msk <= 8; msk <<= 1) { sm += __shfl_xor(sm, msk); qq += __shfl_xor(qq, msk); }
            if (l15 == 0) {
                int oc = m * 16 + grp * 4 + r;
                atomicAdd(&st3[oc], sm);
                atomicAdd(&st3[32 + oc], qq);
            }
        }
    __syncthreads();
    if (t < 32) {
        atomicAdd(&ws[SLOTS3  + t * 64 + slot], st3[t]);
        atomicAdd(&ws[SLOTS3Q + t * 64 + slot], st3[32 + t]);
    }
}

// ---------------------------------------------------------------------------
// K4: out = x + bn3(o), pure float4 stream.
__global__ __launch_bounds__(NT, 8)
void k4_st(const float* __restrict__ x, const float* __restrict__ ws,
           const ushort* __restrict__ oi, float* __restrict__ out) {
    #pragma unroll
    for (int it = 0; it < 8; it++) {
        size_t e = ((size_t)(blockIdx.x * NT + threadIdx.x) + (size_t)it * (2048 * NT)) * 4;
        int oc = (int)((e >> 16) & 31);
        float a3 = ws[FIN3 + oc], b3 = ws[FIN3 + 32 + oc];
        uint2 ov = *(const uint2*)(oi + e);
        float4 xv = *(const float4*)(x + e);
        float4 r;
        r.x = xv.x + bf16lo_to_f(ov.x) * a3 + b3;
        r.y = xv.y + bf16hi_to_f(ov.x) * a3 + b3;
        r.z = xv.z + bf16lo_to_f(ov.y) * a3 + b3;
        r.w = xv.w + bf16hi_to_f(ov.y) * a3 + b3;
        *(float4*)(out + e) = r;
    }
}

__global__ void finalize_k(float* __restrict__ ws, int stage,
                           const float* __restrict__ gamma, const float* __restrict__ beta) {
    int ch = threadIdx.x;
    int nch = (stage == 3) ? 32 : 64;
    if (ch >= nch) return;
    int so = (stage == 1) ? SLOTS1  : (stage == 2) ? SLOTS2  : SLOTS3;
    int sq = (stage == 1) ? SLOTS1Q : (stage == 2) ? SLOTS2Q : SLOTS3Q;
    int fo = (stage == 1) ? FIN1    : (stage == 2) ? FIN2    : FIN3;
    float N = (stage == 1) ? 819200.0f : 524288.0f;
    float sm = 0.f, qq = 0.f;
    for (int j = 0; j < 64; j++) { sm += ws[so + ch*64 + j]; qq += ws[sq + ch*64 + j]; }
    float mean = sm / N;
    float var  = qq / N - mean * mean;
    float rstd = rsqrtf(var + EPSc);
    float a = rstd * gamma[ch];
    ws[fo + ch]       = a;
    ws[fo + nch + ch] = beta[ch] - mean * a;
}

// ---------------------------------------------------------------------------
extern "C" void kernel_launch(void* const* d_in, const int* in_sizes, int n_in,
                              void* d_out, int out_size, void* d_ws, size_t ws_size,
                              hipStream_t stream) {
    const float* x  = (const float*)d_in[0];
    const float* s  = (const float*)d_in[1];
    const float* g1 = (const float*)d_in[2];
    const float* b1 = (const float*)d_in[3];
    const float* g2 = (const float*)d_in[4];
    const float* b2 = (const float*)d_in[5];
    const float* g3 = (const float*)d_in[6];
    const float* b3 = (const float*)d_in[7];
    float* out = (float*)d_out;
    float* ws  = (float*)d_ws;

    hipMemsetAsync(d_ws, 0, STATS_ZERO_FLOATS * sizeof(float), stream);

    ushort* st2 = (ushort*)((char*)d_ws + ST2_OFF);
    ushort* zb  = (ushort*)((char*)d_ws + ZB_OFF);
    ushort* yb  = (ushort*)((char*)d_ws + Y_OFF);
    ushort* oi  = (ushort*)((char*)d_ws + OI_OFF);

    const bool big = ws_size >= NEED_Y;

    transpose_s_bf16p<<<dim3(73, 32, 8), dim3(32, 8), 0, stream>>>(s, st2);
    if (big) {
        k1_mf<1><<<2048, NT, 0, stream>>>(x, st2, yb, ws);
        finalize_k<<<1, 64, 0, stream>>>(ws, 1, g1, b1);
        k2_y<<<2048, NT, 0, stream>>>(yb, st2, zb, ws);
    } else {
        k1_mf<0><<<2048, NT, 0, stream>>>(x, st2, nullptr, ws);
        finalize_k<<<1, 64, 0, stream>>>(ws, 1, g1, b1);
        k2_mf<<<2048, NT, 0, stream>>>(x, st2, zb, ws);
    }
    finalize_k<<<1, 64, 0, stream>>>(ws, 2, g2, b2);
    k3_mf<<<2048, NT, 0, stream>>>(zb, st2, oi, ws);
    finalize_k<<<1, 64, 0, stream>>>(ws, 3, g3, b3);
    k4_st<<<2048, NT, 0, stream>>>(x, ws, oi, out);
}

// Round 10
// 282.362 us; speedup vs baseline: 1.8212x; 1.0086x over previous
//
#include <hip/hip_runtime.h>

#define NT 256

constexpr int R1c = 2048;
constexpr int R2c = 2624;
constexpr float EPSc = 1e-5f;

// ws float offsets (stats)
constexpr int SLOTS1  = 0;
constexpr int SLOTS1Q = 4096;
constexpr int SLOTS2  = 8192;
constexpr int SLOTS2Q = 12288;
constexpr int SLOTS3  = 16384;
constexpr int SLOTS3Q = 18432;
constexpr int FIN1    = 20480;
constexpr int FIN2    = 20608;
constexpr int FIN3    = 20736;
constexpr int STATS_ZERO_FLOATS = 20480;

// ws byte offsets
constexpr size_t ST2_OFF   = 131072;                   // bf16 transposed s
constexpr size_t ST2_BYTES = 8ull * 1024 * 4672 * 2;   // 76,546,048
constexpr size_t ZB_OFF    = ST2_OFF + ST2_BYTES;      // z bf16 [patch][64][64]
constexpr size_t ZB_BYTES  = 8192ull * 4096 * 2;       // 67,108,864
constexpr size_t Y_OFF     = ZB_OFF + ZB_BYTES;        // 143,785,984
constexpr size_t Y_BYTES   = 8192ull * 13312;          // y bf16 [patch][64][104]
constexpr size_t NEED_Y    = Y_OFF + Y_BYTES;          // 252,837,888
constexpr size_t OI_OFF    = Y_OFF;                    // o image overlays dead y

// ---- bf16 helpers -------------------------------------------------------
__device__ __forceinline__ ushort f_to_bf16(float f) {
    union { float f; unsigned int i; } v; v.f = f;
    unsigned int r = (v.i + 0x7fffu + ((v.i >> 16) & 1u)) >> 16;
    return (ushort)r;
}
__device__ __forceinline__ float bf16_to_f(ushort u) {
    union { unsigned int i; float f; } v; v.i = ((unsigned int)u) << 16; return v.f;
}
__device__ __forceinline__ float bf16lo_to_f(unsigned int u) {
    union { unsigned int i; float f; } v; v.i = u << 16; return v.f;
}
__device__ __forceinline__ float bf16hi_to_f(unsigned int u) {
    union { unsigned int i; float f; } v; v.i = u & 0xffff0000u; return v.f;
}
__device__ __forceinline__ unsigned int pack_bf16(float lo, float hi) {
    return (unsigned int)f_to_bf16(lo) | ((unsigned int)f_to_bf16(hi) << 16);
}

typedef short bf16x8 __attribute__((ext_vector_type(8)));
typedef float f32x4  __attribute__((ext_vector_type(4)));
union FR { uint4 u4; bf16x8 v; ushort s[8]; };

__device__ __forceinline__ f32x4 mfma16(bf16x8 a, bf16x8 b, f32x4 c) {
    return __builtin_amdgcn_mfma_f32_16x16x32_bf16(a, b, c, 0, 0, 0);
}

// ---------------------------------------------------------------------------
// Transpose s [8][4672][1024] fp32 -> st bf16 [8][1024][4672]
__global__ __launch_bounds__(256)
void transpose_s_bf16p(const float* __restrict__ s, ushort* __restrict__ st) {
    __shared__ float tile[64][33];
    const int bi = blockIdx.z;
    const int p0 = blockIdx.x * 64;
    const int q0 = blockIdx.y * 32;
    const int tx = threadIdx.x, ty = threadIdx.y;
    const float* sb = s + (size_t)bi * 4672 * 1024;
    #pragma unroll
    for (int r = ty; r < 64; r += 8)
        tile[r][tx] = sb[(size_t)(p0 + r) * 1024 + q0 + tx];
    __syncthreads();
    unsigned int* stu = (unsigned int*)(st + (size_t)bi * 1024 * 4672);
    #pragma unroll
    for (int rr = ty; rr < 32; rr += 8) {
        int q = q0 + rr;
        unsigned int v = pack_bf16(tile[2*tx][rr], tile[2*tx + 1][rr]);
        stu[((size_t)q * 4672 + p0) / 2 + tx] = v;
    }
}

// ---------------------------------------------------------------------------
// NEW fast path: grid 4096, block = 2 patches, 2 waves per patch (m-split).
// decode: bi=blk>>9, f=(blk>>4)&31, jb=blk&15, g0=jb*2; wave: pl_=w>>1, mh=w&1.

// K1: stage-1 MFMA + stats1 + y bf16 stream-out [patch][64][104].
__global__ __launch_bounds__(NT, 2)
void k1_s(const float* __restrict__ x, const ushort* __restrict__ st2,
          ushort* __restrict__ ybuf, float* __restrict__ ws) {
    __shared__ ushort frB[2 * 3584];
    __shared__ float st1[128];
    const int t = threadIdx.x, blk = blockIdx.x;
    const int bi = blk >> 9, f = (blk >> 4) & 31, jb = blk & 15;
    const int g0 = jb * 2, slot = blk & 63;
    const int w = t >> 6, l = t & 63, l15 = l & 15, grp = l >> 4;
    const int pl_ = w >> 1, mh = w & 1;
    const int patch = bi * 1024 + f * 32 + g0 + pl_;

    if (t < 128) {
        st1[t] = 0.f;
        int p = t >> 6, e = t & 63;             // zero pads: frag n=6, px 100..111
        if ((e & 15) >= 4)
            ((uint4*)frB)[p * 448 + 384 + e] = make_uint4(0u, 0u, 0u, 0u);
    }
    const ushort* wp = st2 + (size_t)patch * 4672;
    FR aw[2];
    #pragma unroll
    for (int i = 0; i < 2; i++)
        aw[i].u4 = ((const uint4*)wp)[((mh * 2 + i) * 16 + l15) * 4 + grp];

    // x staging: 2 patches, cols g0*8-4 .. g0*8+19 (6 float4 segs), reflect halo
    const float* xb = x + (size_t)bi * 32 * 65536;
    for (int i = t; i < 1920; i += NT) {
        int c = i / 60, rem = i - c * 60;
        int r = rem / 6, seg = rem - r * 6;
        int row = f * 8 - 1 + r; row = row < 0 ? -row : (row > 255 ? 510 - row : row);
        int col0 = g0 * 8 - 4 + seg * 4;
        float v4[4];
        if (col0 >= 0 && col0 <= 252) {
            float4 vv = *(const float4*)(xb + (size_t)c * 65536 + row * 256 + col0);
            v4[0] = vv.x; v4[1] = vv.y; v4[2] = vv.z; v4[3] = vv.w;
        } else {
            #pragma unroll
            for (int d = 0; d < 4; d++) {
                int cc = col0 + d; cc = cc < 0 ? -cc : (cc > 255 ? 510 - cc : cc);
                v4[d] = xb[(size_t)c * 65536 + row * 256 + cc];
            }
        }
        int grpc = c >> 3, j = c & 7;
        #pragma unroll
        for (int d = 0; d < 4; d++) {
            int u = col0 + d - g0 * 8;
            ushort hv = f_to_bf16(v4[d]);
            #pragma unroll
            for (int p = 0; p < 2; p++) {
                int pc = u - 8 * p + 1;
                if (pc >= 0 && pc <= 9) {
                    int px = r * 10 + pc;
                    frB[p * 3584 + ((px >> 4) * 64 + grpc * 16 + (px & 15)) * 8 + j] = hv;
                }
            }
        }
    }
    __syncthreads();

    FR b[7];
    const uint4* bp = (const uint4*)(frB + pl_ * 3584);
    #pragma unroll
    for (int n = 0; n < 7; n++) b[n].u4 = bp[n * 64 + l];
    __syncthreads();    // both waves of each patch done reading frags -> overlay safe

    ushort* slice = frB + pl_ * 3584 + mh * 1792;   // own 16ch x 106 slice
    unsigned int* sliceU = (unsigned int*)slice;
    uint4* yb4 = (uint4*)ybuf + (size_t)patch * 832;
    float s4[8], q4[8];
    #pragma unroll
    for (int i = 0; i < 8; i++) { s4[i] = 0.f; q4[i] = 0.f; }
    #pragma unroll
    for (int i = 0; i < 2; i++) {
        int mm = mh * 2 + i;
        #pragma unroll
        for (int n = 0; n < 7; n++) {
            f32x4 z = {0.f, 0.f, 0.f, 0.f};
            f32x4 c = mfma16(aw[i].v, b[n].v, z);
            int px = n * 16 + l15;
            #pragma unroll
            for (int r = 0; r < 4; r++) {
                float v = c[r]; s4[i*4+r] += v; q4[i*4+r] += v * v;
                if (px < 100) slice[(grp * 4 + r) * 106 + px] = f_to_bf16(v);
            }
        }
        for (int k = l; k < 208; k += 64) {
            int ch2 = k / 13, sub = k - ch2 * 13;
            int ub = ch2 * 53 + sub * 4;
            yb4[mm * 208 + k] = make_uint4(sliceU[ub], sliceU[ub+1], sliceU[ub+2], sliceU[ub+3]);
        }
    }
    #pragma unroll
    for (int i = 0; i < 8; i++) {
        float sm = s4[i], qq = q4[i];
        #pragma unroll
        for (int msk = 1; msk <= 8; msk <<= 1) { sm += __shfl_xor(sm, msk); qq += __shfl_xor(qq, msk); }
        if (l15 == 0) {
            int ch = (mh * 2 + (i >> 2)) * 16 + grp * 4 + (i & 3);
            atomicAdd(&st1[ch], sm);
            atomicAdd(&st1[64 + ch], qq);
        }
    }
    __syncthreads();
    if (t < 64) {
        atomicAdd(&ws[SLOTS1  + t * 64 + slot], st1[t]);
        atomicAdd(&ws[SLOTS1Q + t * 64 + slot], st1[64 + t]);
    }
}

// ---------------------------------------------------------------------------
// K2: y bf16 coalesced read -> BN1+relu6 -> depthwise 3x3 -> stats2 -> z bf16.
__global__ __launch_bounds__(NT, 2)
void k2_s(const ushort* __restrict__ ybuf, const ushort* __restrict__ st2,
          ushort* __restrict__ zbuf, float* __restrict__ ws) {
    __shared__ ushort slc[4 * 1696];        // per-wave [16 ch][106]
    __shared__ unsigned int w2L[2 * 288];
    __shared__ float fin_s[128];
    __shared__ float st2s[128];
    const int t = threadIdx.x, blk = blockIdx.x;
    const int bi = blk >> 9, f = (blk >> 4) & 31, jb = blk & 15;
    const int g0 = jb * 2, slot = blk & 63;
    const int w = t >> 6, l = t & 63;
    const int pl_ = w >> 1, mh = w & 1;
    const int ch_l = l >> 2, quad = l & 3, p0 = quad * 2;
    const int patch = bi * 1024 + f * 32 + g0 + pl_;

    if (t < 128) { fin_s[t] = ws[FIN1 + t]; st2s[t] = 0.f; }
    for (int k = t; k < 576; k += NT) {
        int p = (k >= 288) ? 1 : 0;
        int kk = k - p * 288;
        const unsigned int* src = (const unsigned int*)(st2 + (size_t)(bi*1024 + f*32 + g0 + p) * 4672 + R1c);
        w2L[k] = src[kk];
    }
    __syncthreads();

    const uint4* yb4 = (const uint4*)ybuf + (size_t)patch * 832;
    ushort* slice = slc + w * 1696;
    unsigned int* sliceU = (unsigned int*)slice;
    const ushort* w2u = (const ushort*)(w2L + pl_ * 288);
    ushort* zp0 = zbuf + (size_t)patch * 4096;

    #pragma unroll
    for (int i = 0; i < 2; i++) {
        int mm = mh * 2 + i;
        for (int k = l; k < 208; k += 64) {
            uint4 v = yb4[mm * 208 + k];
            int ch2 = k / 13, sub = k - ch2 * 13;
            int ch = mm * 16 + ch2;
            float a1 = fin_s[ch], b1 = fin_s[64 + ch];
            unsigned int uu[4] = {v.x, v.y, v.z, v.w};
            int ub = ch2 * 53 + sub * 4;
            #pragma unroll
            for (int kk = 0; kk < 4; kk++) {
                float lo = fminf(fmaxf(bf16lo_to_f(uu[kk]) * a1 + b1, 0.f), 6.f);
                float hi = fminf(fmaxf(bf16hi_to_f(uu[kk]) * a1 + b1, 0.f), 6.f);
                sliceU[ub + kk] = pack_bf16(lo, hi);
            }
        }
        // depthwise 3x3 (wave-local slice)
        float yv[4][10];
        #pragma unroll
        for (int rr = 0; rr < 4; rr++) {
            int base = ch_l * 53 + (p0 + rr) * 5;
            #pragma unroll
            for (int k = 0; k < 5; k++) {
                unsigned int u = sliceU[base + k];
                yv[rr][2*k] = bf16lo_to_f(u); yv[rr][2*k+1] = bf16hi_to_f(u);
            }
        }
        float wt[9];
        #pragma unroll
        for (int k = 0; k < 9; k++) wt[k] = bf16_to_f(w2u[(mm * 16 + ch_l) * 9 + k]);
        float za[2][8];
        #pragma unroll
        for (int rr = 0; rr < 2; rr++)
            #pragma unroll
            for (int q = 0; q < 8; q++) za[rr][q] = 0.f;
        #pragma unroll
        for (int u = 0; u < 3; u++)
            #pragma unroll
            for (int v = 0; v < 3; v++) {
                float wv = wt[u * 3 + v];
                #pragma unroll
                for (int rr = 0; rr < 2; rr++)
                    #pragma unroll
                    for (int q = 0; q < 8; q++)
                        za[rr][q] += wv * yv[rr + u][q + v];
            }
        float zs = 0.f, zq = 0.f;
        #pragma unroll
        for (int rr = 0; rr < 2; rr++)
            #pragma unroll
            for (int q = 0; q < 8; q++) { float v = za[rr][q]; zs += v; zq += v * v; }
        zs += __shfl_xor(zs, 1); zs += __shfl_xor(zs, 2);
        zq += __shfl_xor(zq, 1); zq += __shfl_xor(zq, 2);
        if (quad == 0) {
            atomicAdd(&st2s[mm * 16 + ch_l], zs);
            atomicAdd(&st2s[64 + mm * 16 + ch_l], zq);
        }
        ushort* zp = zp0 + (mm * 16 + ch_l) * 64 + p0 * 8;
        uint4 pk0, pk1;
        pk0.x = pack_bf16(za[0][0], za[0][1]); pk0.y = pack_bf16(za[0][2], za[0][3]);
        pk0.z = pack_bf16(za[0][4], za[0][5]); pk0.w = pack_bf16(za[0][6], za[0][7]);
        pk1.x = pack_bf16(za[1][0], za[1][1]); pk1.y = pack_bf16(za[1][2], za[1][3]);
        pk1.z = pack_bf16(za[1][4], za[1][5]); pk1.w = pack_bf16(za[1][6], za[1][7]);
        *(uint4*)zp = pk0;
        *(uint4*)(zp + 8) = pk1;
    }
    __syncthreads();
    if (t < 64) {
        atomicAdd(&ws[SLOTS2  + t * 64 + slot], st2s[t]);
        atomicAdd(&ws[SLOTS2Q + t * 64 + slot], st2s[64 + t]);
    }
}

// ---------------------------------------------------------------------------
// K3: z -> BN2+relu6 -> MFMA (M=32,N=64,K=64, m-split) -> stats3 + o image.
__global__ __launch_bounds__(NT, 2)
void k3_s(const ushort* __restrict__ zbuf, const ushort* __restrict__ st2,
          ushort* __restrict__ oi, float* __restrict__ ws) {
    __shared__ ushort zL[2 * 4224];          // per patch [64 ch][66]
    __shared__ float fin2[128];
    __shared__ float st3[64];
    const int t = threadIdx.x, blk = blockIdx.x;
    const int bi = blk >> 9, f = (blk >> 4) & 31, jb = blk & 15;
    const int g0 = jb * 2, slot = blk & 63;
    const int w = t >> 6, l = t & 63, l15 = l & 15, grp = l >> 4;
    const int pl_ = w >> 1, mh = w & 1;
    const int patch = bi * 1024 + f * 32 + g0 + pl_;

    if (t < 128) fin2[t] = ws[FIN2 + t];
    if (t >= 128 && t < 192) st3[t - 128] = 0.f;
    const ushort* wp = st2 + (size_t)patch * 4672;
    FR aw[2];
    #pragma unroll
    for (int ks = 0; ks < 2; ks++)
        aw[ks].u4 = ((const uint4*)(wp + R2c))[(mh * 16 + l15) * 8 + ks * 4 + grp];
    __syncthreads();   // fin2 ready

    // z staging: wave mh stages its half (256 uint4) of own patch
    const uint4* zsrc = (const uint4*)(zbuf + (size_t)patch * 4096);
    unsigned int* zd = (unsigned int*)zL;
    #pragma unroll
    for (int it = 0; it < 4; it++) {
        int i = mh * 256 + it * 64 + l;
        uint4 v = zsrc[i];
        int ch = i >> 3, px0 = (i & 7) * 8;
        float a2 = fin2[ch], b2 = fin2[64 + ch];
        unsigned int uu[4] = {v.x, v.y, v.z, v.w};
        int base = pl_ * 2112 + (ch * 66 + px0) / 2;
        #pragma unroll
        for (int k = 0; k < 4; k++) {
            float lo = fminf(fmaxf(bf16lo_to_f(uu[k]) * a2 + b2, 0.f), 6.f);
            float hi = fminf(fmaxf(bf16hi_to_f(uu[k]) * a2 + b2, 0.f), 6.f);
            zd[base + k] = pack_bf16(lo, hi);
        }
    }
    __syncthreads();   // both waves of patch staged

    FR bfr[2][4];
    #pragma unroll
    for (int ks = 0; ks < 2; ks++)
        #pragma unroll
        for (int n = 0; n < 4; n++)
            #pragma unroll
            for (int j = 0; j < 8; j++)
                bfr[ks][n].s[j] = zL[pl_ * 4224 + (ks * 32 + grp * 8 + j) * 66 + n * 16 + l15];

    float s4[4], q4[4];
    #pragma unroll
    for (int r = 0; r < 4; r++) { s4[r] = 0.f; q4[r] = 0.f; }
    #pragma unroll
    for (int n = 0; n < 4; n++) {
        f32x4 z = {0.f, 0.f, 0.f, 0.f};
        f32x4 c = mfma16(aw[0].v, bfr[0][n].v, z);
        c = mfma16(aw[1].v, bfr[1][n].v, c);
        #pragma unroll
        for (int r = 0; r < 4; r++) {
            float v = c[r];
            s4[r] += v; q4[r] += v * v;
            int oc = mh * 16 + grp * 4 + r;
            int px = n * 16 + l15, p = px >> 3, q = px & 7;
            oi[((size_t)(bi * 32 + oc) * 256 + f * 8 + p) * 256 + (g0 + pl_) * 8 + q] = f_to_bf16(v);
        }
    }
    #pragma unroll
    for (int r = 0; r < 4; r++) {
        float sm = s4[r], qq = q4[r];
        #pragma unroll
        for (int msk = 1; msk <= 8; msk <<= 1) { sm += __shfl_xor(sm, msk); qq += __shfl_xor(qq, msk); }
        if (l15 == 0) {
            int oc = mh * 16 + grp * 4 + r;
            atomicAdd(&st3[oc], sm);
            atomicAdd(&st3[32 + oc], qq);
        }
    }
    __syncthreads();
    if (t < 32) {
        atomicAdd(&ws[SLOTS3  + t * 64 + slot], st3[t]);
        atomicAdd(&ws[SLOTS3Q + t * 64 + slot], st3[32 + t]);
    }
}

// ---------------------------------------------------------------------------
// K4: out = x + bn3(o), pure float4 stream.
__global__ __launch_bounds__(NT, 8)
void k4_st(const float* __restrict__ x, const float* __restrict__ ws,
           const ushort* __restrict__ oi, float* __restrict__ out) {
    #pragma unroll
    for (int it = 0; it < 8; it++) {
        size_t e = ((size_t)(blockIdx.x * NT + threadIdx.x) + (size_t)it * (2048 * NT)) * 4;
        int oc = (int)((e >> 16) & 31);
        float a3 = ws[FIN3 + oc], b3 = ws[FIN3 + 32 + oc];
        uint2 ov = *(const uint2*)(oi + e);
        float4 xv = *(const float4*)(x + e);
        float4 r;
        r.x = xv.x + bf16lo_to_f(ov.x) * a3 + b3;
        r.y = xv.y + bf16hi_to_f(ov.x) * a3 + b3;
        r.z = xv.z + bf16lo_to_f(ov.y) * a3 + b3;
        r.w = xv.w + bf16hi_to_f(ov.y) * a3 + b3;
        *(float4*)(out + e) = r;
    }
}

__global__ void finalize_k(float* __restrict__ ws, int stage,
                           const float* __restrict__ gamma, const float* __restrict__ beta) {
    int ch = threadIdx.x;
    int nch = (stage == 3) ? 32 : 64;
    if (ch >= nch) return;
    int so = (stage == 1) ? SLOTS1  : (stage == 2) ? SLOTS2  : SLOTS3;
    int sq = (stage == 1) ? SLOTS1Q : (stage == 2) ? SLOTS2Q : SLOTS3Q;
    int fo = (stage == 1) ? FIN1    : (stage == 2) ? FIN2    : FIN3;
    float N = (stage == 1) ? 819200.0f : 524288.0f;
    float sm = 0.f, qq = 0.f;
    for (int j = 0; j < 64; j++) { sm += ws[so + ch*64 + j]; qq += ws[sq + ch*64 + j]; }
    float mean = sm / N;
    float var  = qq / N - mean * mean;
    float rstd = rsqrtf(var + EPSc);
    float a = rstd * gamma[ch];
    ws[fo + ch]       = a;
    ws[fo + nch + ch] = beta[ch] - mean * a;
}

// ---------------------------------------------------------------------------
// ===== Fallback kernels (R8 path, grid 2048, verbatim) =====
__global__ __launch_bounds__(NT, 4)
void k1_mf(const float* __restrict__ x, const ushort* __restrict__ st2,
           float* __restrict__ ws) {
    __shared__ ushort frB[4 * 3584];
    __shared__ float st1[128];
    const int t = threadIdx.x, blk = blockIdx.x;
    const int bi = blk >> 8, f = (blk >> 3) & 31, jb = blk & 7;
    const int g0 = jb * 4, slot = blk & 63;
    const int w = t >> 6, l = t & 63, l15 = l & 15, grp = l >> 4;

    if (t < 128) st1[t] = 0.f;
    {
        int p = t >> 6, e = t & 63;
        if ((e & 15) >= 4)
            ((uint4*)frB)[p * 448 + 384 + e] = make_uint4(0u, 0u, 0u, 0u);
    }
    const ushort* wp = st2 + (size_t)(bi * 1024 + f * 32 + g0 + w) * 4672;
    FR aw[4];
    #pragma unroll
    for (int m = 0; m < 4; m++) aw[m].u4 = ((const uint4*)wp)[(m * 16 + l15) * 4 + grp];

    const float* xb = x + (size_t)bi * 32 * 65536;
    for (int i = t; i < 3200; i += NT) {
        int c = i / 100, rem = i - c * 100;
        int r = rem / 10, seg = rem - r * 10;
        int row = f * 8 - 1 + r; row = row < 0 ? -row : (row > 255 ? 510 - row : row);
        int col0 = g0 * 8 - 4 + seg * 4;
        float v4[4];
        if (col0 >= 0 && col0 <= 252) {
            float4 vv = *(const float4*)(xb + (size_t)c * 65536 + row * 256 + col0);
            v4[0] = vv.x; v4[1] = vv.y; v4[2] = vv.z; v4[3] = vv.w;
        } else {
            #pragma unroll
            for (int d = 0; d < 4; d++) {
                int cc = col0 + d; cc = cc < 0 ? -cc : (cc > 255 ? 510 - cc : cc);
                v4[d] = xb[(size_t)c * 65536 + row * 256 + cc];
            }
        }
        int grpc = c >> 3, j = c & 7;
        #pragma unroll
        for (int d = 0; d < 4; d++) {
            int u = col0 + d - g0 * 8;
            ushort hv = f_to_bf16(v4[d]);
            #pragma unroll
            for (int p = 0; p < 4; p++) {
                int pc = u - 8 * p + 1;
                if (pc >= 0 && pc <= 9) {
                    int px = r * 10 + pc;
                    frB[p * 3584 + ((px >> 4) * 64 + grpc * 16 + (px & 15)) * 8 + j] = hv;
                }
            }
        }
    }
    __syncthreads();

    FR b[7];
    const uint4* bp = (const uint4*)(frB + w * 3584);
    #pragma unroll
    for (int n = 0; n < 7; n++) b[n].u4 = bp[n * 64 + l];
    float s4[16], q4[16];
    #pragma unroll
    for (int i = 0; i < 16; i++) { s4[i] = 0.f; q4[i] = 0.f; }
    #pragma unroll
    for (int m = 0; m < 4; m++) {
        #pragma unroll
        for (int n = 0; n < 7; n++) {
            f32x4 z = {0.f, 0.f, 0.f, 0.f};
            f32x4 c = mfma16(aw[m].v, b[n].v, z);
            #pragma unroll
            for (int r = 0; r < 4; r++) { float v = c[r]; s4[m*4+r] += v; q4[m*4+r] += v * v; }
        }
    }
    #pragma unroll
    for (int i = 0; i < 16; i++) {
        float sm = s4[i], qq = q4[i];
        #pragma unroll
        for (int msk = 1; msk <= 8; msk <<= 1) { sm += __shfl_xor(sm, msk); qq += __shfl_xor(qq, msk); }
        if (l15 == 0) {
            int ch = (i >> 2) * 16 + grp * 4 + (i & 3);
            atomicAdd(&st1[ch], sm);
            atomicAdd(&st1[64 + ch], qq);
        }
    }
    __syncthreads();
    if (t < 64) {
        atomicAdd(&ws[SLOTS1  + t * 64 + slot], st1[t]);
        atomicAdd(&ws[SLOTS1Q + t * 64 + slot], st1[64 + t]);
    }
}

__global__ __launch_bounds__(NT, 3)
void k2_mf(const float* __restrict__ x, const ushort* __restrict__ st2,
           ushort* __restrict__ zbuf, float* __restrict__ ws) {
    __shared__ ushort frB[4 * 3584];
    __shared__ unsigned int w2L[4 * 288];
    __shared__ float fin_s[128];
    const int t = threadIdx.x, blk = blockIdx.x;
    const int bi = blk >> 8, f = (blk >> 3) & 31, jb = blk & 7;
    const int g0 = jb * 4, slot = blk & 63;
    const int w = t >> 6, l = t & 63, l15 = l & 15, grp = l >> 4;
    const int patch = bi * 1024 + f * 32 + g0 + w;

    if (t < 128) fin_s[t] = ws[FIN1 + t];
    {
        int p = t >> 6, e = t & 63;
        if ((e & 15) >= 4)
            ((uint4*)frB)[p * 448 + 384 + e] = make_uint4(0u, 0u, 0u, 0u);
    }
    const ushort* wp = st2 + (size_t)patch * 4672;
    FR aw[4];
    #pragma unroll
    for (int m = 0; m < 4; m++) aw[m].u4 = ((const uint4*)wp)[(m * 16 + l15) * 4 + grp];
    for (int k = l; k < 288; k += 64) w2L[w * 288 + k] = ((const unsigned int*)(wp + R1c))[k];

    const float* xb = x + (size_t)bi * 32 * 65536;
    for (int i = t; i < 3200; i += NT) {
        int c = i / 100, rem = i - c * 100;
        int r = rem / 10, seg = rem - r * 10;
        int row = f * 8 - 1 + r; row = row < 0 ? -row : (row > 255 ? 510 - row : row);
        int col0 = g0 * 8 - 4 + seg * 4;
        float v4[4];
        if (col0 >= 0 && col0 <= 252) {
            float4 vv = *(const float4*)(xb + (size_t)c * 65536 + row * 256 + col0);
            v4[0] = vv.x; v4[1] = vv.y; v4[2] = vv.z; v4[3] = vv.w;
        } else {
            #pragma unroll
            for (int d = 0; d < 4; d++) {
                int cc = col0 + d; cc = cc < 0 ? -cc : (cc > 255 ? 510 - cc : cc);
                v4[d] = xb[(size_t)c * 65536 + row * 256 + cc];
            }
        }
        int grpc = c >> 3, j = c & 7;
        #pragma unroll
        for (int d = 0; d < 4; d++) {
            int u = col0 + d - g0 * 8;
            ushort hv = f_to_bf16(v4[d]);
            #pragma unroll
            for (int p = 0; p < 4; p++) {
                int pc = u - 8 * p + 1;
                if (pc >= 0 && pc <= 9) {
                    int px = r * 10 + pc;
                    frB[p * 3584 + ((px >> 4) * 64 + grpc * 16 + (px & 15)) * 8 + j] = hv;
                }
            }
        }
    }
    __syncthreads();

    FR b[7];
    const uint4* bp = (const uint4*)(frB + w * 3584);
    #pragma unroll
    for (int n = 0; n < 7; n++) b[n].u4 = bp[n * 64 + l];

    ushort* slice = frB + w * 3584;
    const ushort* w2u = (const ushort*)(w2L + w * 288);
    const int ch_l = l >> 2, quad = l & 3, p0 = quad * 2;
    float zsum[4], zsq[4];
    ushort* zp0 = zbuf + (size_t)patch * 4096;

    #pragma unroll
    for (int m = 0; m < 4; m++) {
        #pragma unroll
        for (int n = 0; n < 7; n++) {
            f32x4 z = {0.f, 0.f, 0.f, 0.f};
            f32x4 c = mfma16(aw[m].v, b[n].v, z);
            int px = n * 16 + l15;
            if (px < 100) {
                #pragma unroll
                for (int r = 0; r < 4; r++) {
                    int ch = m * 16 + grp * 4 + r;
                    float v = fminf(fmaxf(c[r] * fin_s[ch] + fin_s[64 + ch], 0.f), 6.f);
                    slice[(grp * 4 + r) * 102 + px] = f_to_bf16(v);
                }
            }
        }
        float yv[4][10];
        const unsigned int* sl32 = (const unsigned int*)slice;
        #pragma unroll
        for (int rr = 0; rr < 4; rr++) {
            int base = ch_l * 51 + (p0 + rr) * 5;
            #pragma unroll
            for (int k = 0; k < 5; k++) {
                unsigned int u = sl32[base + k];
                yv[rr][2*k] = bf16lo_to_f(u); yv[rr][2*k+1] = bf16hi_to_f(u);
            }
        }
        float wt[9];
        #pragma unroll
        for (int k = 0; k < 9; k++) wt[k] = bf16_to_f(w2u[(m * 16 + ch_l) * 9 + k]);
        float za[2][8];
        #pragma unroll
        for (int rr = 0; rr < 2; rr++)
            #pragma unroll
            for (int q = 0; q < 8; q++) za[rr][q] = 0.f;
        #pragma unroll
        for (int u = 0; u < 3; u++)
            #pragma unroll
            for (int v = 0; v < 3; v++) {
                float wv = wt[u * 3 + v];
                #pragma unroll
                for (int rr = 0; rr < 2; rr++)
                    #pragma unroll
                    for (int q = 0; q < 8; q++)
                        za[rr][q] += wv * yv[rr + u][q + v];
            }
        float zs = 0.f, zq = 0.f;
        #pragma unroll
        for (int rr = 0; rr < 2; rr++)
            #pragma unroll
            for (int q = 0; q < 8; q++) { float v = za[rr][q]; zs += v; zq += v * v; }
        zsum[m] = zs; zsq[m] = zq;
        ushort* zp = zp0 + (m * 16 + ch_l) * 64 + p0 * 8;
        uint4 pk0, pk1;
        pk0.x = pack_bf16(za[0][0], za[0][1]); pk0.y = pack_bf16(za[0][2], za[0][3]);
        pk0.z = pack_bf16(za[0][4], za[0][5]); pk0.w = pack_bf16(za[0][6], za[0][7]);
        pk1.x = pack_bf16(za[1][0], za[1][1]); pk1.y = pack_bf16(za[1][2], za[1][3]);
        pk1.z = pack_bf16(za[1][4], za[1][5]); pk1.w = pack_bf16(za[1][6], za[1][7]);
        *(uint4*)zp = pk0;
        *(uint4*)(zp + 8) = pk1;
    }
    __syncthreads();
    if (t < 128) fin_s[t] = 0.f;
    __syncthreads();
    #pragma unroll
    for (int m = 0; m < 4; m++) {
        float zs = zsum[m], zq = zsq[m];
        zs += __shfl_xor(zs, 1); zs += __shfl_xor(zs, 2);
        zq += __shfl_xor(zq, 1); zq += __shfl_xor(zq, 2);
        if (quad == 0) {
            atomicAdd(&fin_s[m * 16 + ch_l], zs);
            atomicAdd(&fin_s[64 + m * 16 + ch_l], zq);
        }
    }
    __syncthreads();
    if (t < 64) {
        atomicAdd(&ws[SLOTS2  + t * 64 + slot], fin_s[t]);
        atomicAdd(&ws[SLOTS2Q + t * 64 + slot], fin_s[64 + t]);
    }
}

__global__ __launch_bounds__(NT, 4)
void k3_mf(const ushort* __restrict__ zbuf, const ushort* __restrict__ st2,
           ushort* __restrict__ oi, float* __restrict__ ws) {
    __shared__ ushort zL[4 * 4224];
    __shared__ float fin2[128];
    __shared__ float st3[64];
    const int t = threadIdx.x, blk = blockIdx.x;
    const int bi = blk >> 8, f = (blk >> 3) & 31, jb = blk & 7;
    const int g0 = jb * 4, slot = blk & 63;
    const int w = t >> 6, l = t & 63, l15 = l & 15, grp = l >> 4;
    const int patch = bi * 1024 + f * 32 + g0 + w;

    if (t < 128) fin2[t] = ws[FIN2 + t];
    if (t >= 128 && t < 192) st3[t - 128] = 0.f;
    const ushort* wp = st2 + (size_t)patch * 4672;
    FR aw[2][2];
    #pragma unroll
    for (int m = 0; m < 2; m++)
        #pragma unroll
        for (int ks = 0; ks < 2; ks++)
            aw[m][ks].u4 = ((const uint4*)(wp + R2c))[(m * 16 + l15) * 8 + ks * 4 + grp];
    __syncthreads();

    const uint4* zsrc = (const uint4*)(zbuf + (size_t)patch * 4096);
    unsigned int* zd = (unsigned int*)zL;
    #pragma unroll
    for (int it = 0; it < 8; it++) {
        int i = l + 64 * it;
        uint4 v = zsrc[i];
        int ch = i >> 3, px0 = (i & 7) * 8;
        float a2 = fin2[ch], b2 = fin2[64 + ch];
        unsigned int uu[4] = {v.x, v.y, v.z, v.w};
        int base = w * 2112 + (ch * 66 + px0) / 2;
        #pragma unroll
        for (int k = 0; k < 4; k++) {
            float lo = fminf(fmaxf(bf16lo_to_f(uu[k]) * a2 + b2, 0.f), 6.f);
            float hi = fminf(fmaxf(bf16hi_to_f(uu[k]) * a2 + b2, 0.f), 6.f);
            zd[base + k] = pack_bf16(lo, hi);
        }
    }
    FR bfr[2][4];
    #pragma unroll
    for (int ks = 0; ks < 2; ks++)
        #pragma unroll
        for (int n = 0; n < 4; n++)
            #pragma unroll
            for (int j = 0; j < 8; j++)
                bfr[ks][n].s[j] = zL[w * 4224 + (ks * 32 + grp * 8 + j) * 66 + n * 16 + l15];

    float s4[2][4], q4[2][4];
    #pragma unroll
    for (int m = 0; m < 2; m++)
        #pragma unroll
        for (int r = 0; r < 4; r++) { s4[m][r] = 0.f; q4[m][r] = 0.f; }
    #pragma unroll
    for (int m = 0; m < 2; m++)
        #pragma unroll
        for (int n = 0; n < 4; n++) {
            f32x4 z = {0.f, 0.f, 0.f, 0.f};
            f32x4 c = mfma16(aw[m][0].v, bfr[0][n].v, z);
            c = mfma16(aw[m][1].v, bfr[1][n].v, c);
            #pragma unroll
            for (int r = 0; r < 4; r++) {
                float v = c[r];
                s4[m][r] += v; q4[m][r] += v * v;
                int oc = m * 16 + grp * 4 + r;
                int px = n * 16 + l15, p = px >> 3, q = px & 7;
                oi[((size_t)(bi * 32 + oc) * 256 + f * 8 + p) * 256 + (g0 + w) * 8 + q] = f_to_bf16(v);
            }
        }
    #pragma unroll
    for (int m = 0; m < 2; m++)
        #pragma unroll
        for (int r = 0; r < 4; r++) {
            float sm = s4[m][r], qq = q4[m][r];
            #pragma unroll
            for (int msk = 1; msk <= 8; msk <<= 1) { sm += __shfl_xor(sm, msk); qq += __shfl_xor(qq, msk); }
            if (l15 == 0) {
                int oc = m * 16 + grp * 4 + r;
                atomicAdd(&st3[oc], sm);
                atomicAdd(&st3[32 + oc], qq);
            }
        }
    __syncthreads();
    if (t < 32) {
        atomicAdd(&ws[SLOTS3  + t * 64 + slot], st3[t]);
        atomicAdd(&ws[SLOTS3Q + t * 64 + slot], st3[32 + t]);
    }
}

// ---------------------------------------------------------------------------
extern "C" void kernel_launch(void* const* d_in, const int* in_sizes, int n_in,
                              void* d_out, int out_size, void* d_ws, size_t ws_size,
                              hipStream_t stream) {
    const float* x  = (const float*)d_in[0];
    const float* s  = (const float*)d_in[1];
    const float* g1 = (const float*)d_in[2];
    const float* b1 = (const float*)d_in[3];
    const float* g2 = (const float*)d_in[4];
    const float* b2 = (const float*)d_in[5];
    const float* g3 = (const float*)d_in[6];
    const float* b3 = (const float*)d_in[7];
    float* out = (float*)d_out;
    float* ws  = (float*)d_ws;

    hipMemsetAsync(d_ws, 0, STATS_ZERO_FLOATS * sizeof(float), stream);

    ushort* st2 = (ushort*)((char*)d_ws + ST2_OFF);
    ushort* zb  = (ushort*)((char*)d_ws + ZB_OFF);
    ushort* yb  = (ushort*)((char*)d_ws + Y_OFF);
    ushort* oi  = (ushort*)((char*)d_ws + OI_OFF);

    const bool big = ws_size >= NEED_Y;

    transpose_s_bf16p<<<dim3(73, 32, 8), dim3(32, 8), 0, stream>>>(s, st2);
    if (big) {
        k1_s<<<4096, NT, 0, stream>>>(x, st2, yb, ws);
        finalize_k<<<1, 64, 0, stream>>>(ws, 1, g1, b1);
        k2_s<<<4096, NT, 0, stream>>>(yb, st2, zb, ws);
        finalize_k<<<1, 64, 0, stream>>>(ws, 2, g2, b2);
        k3_s<<<4096, NT, 0, stream>>>(zb, st2, oi, ws);
    } else {
        k1_mf<<<2048, NT, 0, stream>>>(x, st2, ws);
        finalize_k<<<1, 64, 0, stream>>>(ws, 1, g1, b1);
        k2_mf<<<2048, NT, 0, stream>>>(x, st2, zb, ws);
        finalize_k<<<1, 64, 0, stream>>>(ws, 2, g2, b2);
        k3_mf<<<2048, NT, 0, stream>>>(zb, st2, oi, ws);
    }
    finalize_k<<<1, 64, 0, stream>>>(ws, 3, g3, b3);
    k4_st<<<2048, NT, 0, stream>>>(x, ws, oi, out);
}